// Round 9
// baseline (713.779 us; speedup 1.0000x reference)
//
#include <hip/hip_runtime.h>

typedef unsigned short u16;
typedef __attribute__((ext_vector_type(8))) __bf16 bf16x8;
typedef __attribute__((ext_vector_type(4))) float f32x4;

__device__ __forceinline__ float bf2f(u16 u) {
  union { unsigned int i; float f; } v; v.i = ((unsigned int)u) << 16; return v.f;
}
__device__ __forceinline__ u16 f2bf(float f) {
  unsigned int x = __float_as_uint(f);
  unsigned int r = (x + 0x7fffu + ((x >> 16) & 1u)) >> 16;
  return (u16)r;
}
__device__ __forceinline__ u16 f2bf_fast(float f) {
  return (u16)((__float_as_uint(f) + 0x8000u) >> 16);
}
__device__ __forceinline__ float gelu_f(float x) {
  float u = 0.7978845608028654f * (x + 0.044715f * x * x * x);
  float t = 1.0f - 2.0f / (__expf(2.0f * u) + 1.0f);
  return 0.5f * x * (1.0f + t);
}
// async global->LDS, 16B per lane. l must be wave-uniform base.
__device__ __forceinline__ void gl_lds16(const u16* g, u16* l) {
  __builtin_amdgcn_global_load_lds(
      (const __attribute__((address_space(1))) unsigned int*)g,
      (__attribute__((address_space(3))) unsigned int*)l, 16, 0, 0);
}

// ---------------------------------------------------------------------------
__global__ __launch_bounds__(256) void cast_bf16_k(const float* __restrict__ in,
                                                   u16* __restrict__ out, int n4) {
  int i = blockIdx.x * 256 + threadIdx.x;
  if (i >= n4) return;
  float4 v = ((const float4*)in)[i];
  ushort4 o;
  o.x = f2bf(v.x); o.y = f2bf(v.y); o.z = f2bf(v.z); o.w = f2bf(v.w);
  ((ushort4*)out)[i] = o;
}

// ---------------------------------------------------------------------------
// Universal output-row mapping: row' = ((cc>>4)*rs + roff)*16 + (cc&15).
// rs=1,roff=0 -> row'=cc (plain). rs=2,roff=s -> 16-col-block interleave
// (for wi0/wi1 -> wi01T pairing consumed by gemm97 MODE 13).
// ---------------------------------------------------------------------------
__global__ __launch_bounds__(256) void transpose_k(
    const float* __restrict__ in, u16* __restrict__ out, int R, int C,
    long isb, long osb, int rs, int roff) {
  __shared__ u16 tile[32][33];
  in += (size_t)blockIdx.z * isb;
  out += (size_t)blockIdx.z * osb;
  int c0 = blockIdx.x * 32, r0 = blockIdx.y * 32;
  int tx = threadIdx.x & 31, ty = threadIdx.x >> 5;
#pragma unroll
  for (int i = 0; i < 4; ++i) {
    int rr = r0 + ty + i * 8;
    if (rr < R && c0 + tx < C) tile[ty + i * 8][tx] = f2bf(in[(size_t)rr * C + c0 + tx]);
  }
  __syncthreads();
#pragma unroll
  for (int i = 0; i < 4; ++i) {
    int cc = c0 + ty + i * 8;
    if (cc < C && r0 + tx < R) {
      int orow = (((cc >> 4) * rs + roff) << 4) + (cc & 15);
      out[(size_t)orow * R + r0 + tx] = tile[tx][ty + i * 8];
    }
  }
}

// ---------------------------------------------------------------------------
// Batched transpose: z selects source pointer from a by-value struct; dst is
// out + z*zstride. roffz: roff = z (wi0/wi1 interleave) else 0.
// ---------------------------------------------------------------------------
struct TSrc8 { const float* p[8]; };
__global__ __launch_bounds__(256) void transpose8_k(
    TSrc8 srcs, u16* __restrict__ out, int R, int C,
    long zstride, int rs, int roffz) {
  __shared__ u16 tile[32][33];
  const float* __restrict__ in = srcs.p[blockIdx.z];
  out += (size_t)blockIdx.z * zstride;
  const int roff = roffz ? blockIdx.z : 0;
  int c0 = blockIdx.x * 32, r0 = blockIdx.y * 32;
  int tx = threadIdx.x & 31, ty = threadIdx.x >> 5;
#pragma unroll
  for (int i = 0; i < 4; ++i) {
    int rr = r0 + ty + i * 8;
    if (rr < R && c0 + tx < C) tile[ty + i * 8][tx] = f2bf(in[(size_t)rr * C + c0 + tx]);
  }
  __syncthreads();
#pragma unroll
  for (int i = 0; i < 4; ++i) {
    int cc = c0 + ty + i * 8;
    if (cc < C && r0 + tx < R) {
      int orow = (((cc >> 4) * rs + roff) << 4) + (cc & 15);
      out[(size_t)orow * R + r0 + tx] = tile[tx][ty + i * 8];
    }
  }
}

// ---------------------------------------------------------------------------
__global__ __launch_bounds__(256) void bias_tab_k(const float* __restrict__ relpos,
                                                  float* __restrict__ tab) {
  int idx = blockIdx.x * 256 + threadIdx.x;  // 16*1024
  int h = idx >> 10, d = idx & 1023;
  int bucket;
  if (d < 16) bucket = d;
  else {
    int lb = 16 + (int)(logf((float)d * (1.0f / 16.0f)) * (16.0f / logf(8.0f)));
    bucket = lb < 31 ? lb : 31;
  }
  tab[idx] = relpos[h * 32 + bucket];
}

// ---------------------------------------------------------------------------
__global__ __launch_bounds__(256) void prefix_fill_k(
    const float* __restrict__ pK, const float* __restrict__ pV,
    u16* __restrict__ Kd, u16* __restrict__ Vtd, int sSel) {
  int idx = blockIdx.x * 256 + threadIdx.x;  // B*H*32*64 = 131072
  int e = idx & 63, p = (idx >> 6) & 31, h = (idx >> 11) & 15, b = idx >> 15;
  int key = (p < 30) ? p : (1024 + p);  // pads -> 1054,1055
  float kv = 0.f, vv = 0.f;
  if (p < 30) {
    size_t src = ((((size_t)(b * 2 + sSel)) * 30 + p) * 16 + h) * 64 + e;
    kv = pK[src]; vv = pV[src];
  }
  Kd[(((size_t)(b * 16 + h)) * 1056 + key) * 64 + e] = f2bf(kv);
  Vtd[(((size_t)(b * 16 + h)) * 64 + e) * 1056 + key] = f2bf(vv);
}

// ---------------------------------------------------------------------------
__global__ __launch_bounds__(256) void rmsnorm_k(const float* __restrict__ in,
                                                 const float* __restrict__ scale,
                                                 u16* __restrict__ out) {
  const int D = 1024;
  size_t base = (size_t)blockIdx.x * D;
  int t = threadIdx.x;
  float x[4];
#pragma unroll
  for (int i = 0; i < 4; ++i) x[i] = in[base + t + i * 256];
  float s = x[0] * x[0] + x[1] * x[1] + x[2] * x[2] + x[3] * x[3];
#pragma unroll
  for (int off = 1; off < 64; off <<= 1) s += __shfl_xor(s, off, 64);
  __shared__ float ws4[4];
  if ((t & 63) == 0) ws4[t >> 6] = s;
  __syncthreads();
  float tot = ws4[0] + ws4[1] + ws4[2] + ws4[3];
  float r = rsqrtf(tot * (1.0f / D) + 1e-6f);
#pragma unroll
  for (int i = 0; i < 4; ++i) {
    int c = t + i * 256;
    out[base + c] = f2bf(x[i] * r * scale[c]);
  }
}

// ---------------------------------------------------------------------------
// Split-K combine fused into rmsnorm: x = in0 + in1 + res; outs = x (f32,
// may alias in1 -- elementwise same-index read-then-write is safe);
// outn = rmsnorm(x)*scale (bf16).
// ---------------------------------------------------------------------------
__global__ __launch_bounds__(256) void rmsnorm_sum_k(
    const float* __restrict__ in0, const float* __restrict__ in1,
    const float* __restrict__ res, const float* __restrict__ scale,
    u16* __restrict__ outn, float* __restrict__ outs) {
  const int D = 1024;
  size_t base = (size_t)blockIdx.x * D;
  int t = threadIdx.x;
  float x[4];
#pragma unroll
  for (int i = 0; i < 4; ++i) {
    int c = t + i * 256;
    x[i] = in0[base + c] + in1[base + c] + res[base + c];
    outs[base + c] = x[i];
  }
  float s = x[0] * x[0] + x[1] * x[1] + x[2] * x[2] + x[3] * x[3];
#pragma unroll
  for (int off = 1; off < 64; off <<= 1) s += __shfl_xor(s, off, 64);
  __shared__ float ws4[4];
  if ((t & 63) == 0) ws4[t >> 6] = s;
  __syncthreads();
  float tot = ws4[0] + ws4[1] + ws4[2] + ws4[3];
  float r = rsqrtf(tot * (1.0f / D) + 1e-6f);
#pragma unroll
  for (int i = 0; i < 4; ++i) {
    int c = t + i * 256;
    outn[base + c] = f2bf(x[i] * r * scale[c]);
  }
}

// ---------------------------------------------------------------------------
// m97-style MFMA GEMM: C[M][N] = A[M][K-stride] @ Bt[N][K-stride]^T.
// 128x128 tile, BK=32, global_load_lds width-16 staging, unpadded LDS.
// K = row stride of A/Bt; Ks = K-loop length (== K except split-K);
// blockIdx.z selects the K-slice (kbase = z*Ks) for MODE 1.
// Bijective XCD swizzle ONLY for MODE 1 (narrow N; wide-N measured harmful
// in R7: contiguous-chunk swizzle streams the whole B panel per XCD).
// Epilogue MODE:
//  1: split-K f32 partial (z=0 -> out, z=1 -> out2)
//  8: Q scatter (*alpha)
//  11: QKV scatter (sec0 Q *alpha; sec1 K +30; sec2 Vt +30)
//  13: fused gelu-gate, 16-col-block interleaved wi01T: j-tiles (2p,2p+1)
//      are (gate,lin) for the same 16 cols -> out=gelu(gate)*lin, no shfl.
//  14: like 11 but A is per-section: sec0 reads A (xn), sec1/2 read A2
//      (enc16) -- merged cross Q+KV projection.
// Scatter: Q [B,H,1024,64] *alpha; K [B,H,1056,64] +30; Vt [B,H,64,1056] +30
// ---------------------------------------------------------------------------
template <int MODE>
__global__ __launch_bounds__(256) void gemm97(
    const u16* __restrict__ A, const u16* __restrict__ A2,
    const u16* __restrict__ Bt, void* __restrict__ out,
    void* __restrict__ out2, void* __restrict__ out3,
    int M, int N, int K, int Ks, float alpha) {
  const int BK = 32;
  __shared__ __align__(16) u16 As[128 * 32];
  __shared__ __align__(16) u16 Bs[128 * 32];

  const int t = threadIdx.x;
  const int wave = t >> 6, lane = t & 63;
  int m0, n0;
  if (MODE == 1) {
    // XCD-aware bijective swizzle: contiguous chunk of wg per XCD.
    int wgid = blockIdx.y * gridDim.x + blockIdx.x;
    const int cpx = (gridDim.x * gridDim.y) >> 3;
    wgid = (wgid & 7) * cpx + (wgid >> 3);
    m0 = (wgid / gridDim.x) * 128;
    n0 = (wgid % gridDim.x) * 128;
  } else {
    m0 = blockIdx.y * 128;
    n0 = blockIdx.x * 128;
  }
  const int kbase = blockIdx.z * Ks;
  const int fr = lane & 15, fq = lane >> 4;
  const int wm = (wave >> 1) * 64, wn = (wave & 1) * 64;

  const u16* Ause = (MODE == 14 && n0 >= 1024) ? A2 : A;
  const int srow = wave * 32 + (lane >> 2);
  const int scol = (lane & 3) * 8;
  const u16* ag0 = Ause + (size_t)(m0 + srow) * K + kbase + scol;
  const u16* ag1 = ag0 + (size_t)16 * K;
  const u16* bg0 = Bt + (size_t)(n0 + srow) * K + kbase + scol;
  const u16* bg1 = bg0 + (size_t)16 * K;
  u16* al0 = &As[(wave * 32) * 32];
  u16* al1 = &As[(wave * 32 + 16) * 32];
  u16* bl0 = &Bs[(wave * 32) * 32];
  u16* bl1 = &Bs[(wave * 32 + 16) * 32];

  f32x4 acc[16];
#pragma unroll
  for (int i = 0; i < 16; ++i) acc[i] = (f32x4){0.f, 0.f, 0.f, 0.f};

  for (int k0 = 0; k0 < Ks; k0 += BK) {
    gl_lds16(ag0 + k0, al0);
    gl_lds16(ag1 + k0, al1);
    gl_lds16(bg0 + k0, bl0);
    gl_lds16(bg1 + k0, bl1);
    __syncthreads();
    bf16x8 af[4], bf[4];
#pragma unroll
    for (int i = 0; i < 4; ++i)
      af[i] = *(const bf16x8*)&As[(wm + i * 16 + fr) * 32 + fq * 8];
#pragma unroll
    for (int j = 0; j < 4; ++j)
      bf[j] = *(const bf16x8*)&Bs[(wn + j * 16 + fr) * 32 + fq * 8];
#pragma unroll
    for (int i = 0; i < 4; ++i)
#pragma unroll
      for (int j = 0; j < 4; ++j)
        acc[i * 4 + j] = __builtin_amdgcn_mfma_f32_16x16x32_bf16(
            af[i], bf[j], acc[i * 4 + j], 0, 0, 0);
    __syncthreads();
  }

  // epilogue: D row = fq*4 + reg, col = fr
#pragma unroll
  for (int i = 0; i < 4; ++i) {
#pragma unroll
    for (int rr = 0; rr < 4; ++rr) {
      long gm = (long)m0 + wm + i * 16 + fq * 4 + rr;
      if (MODE == 13) {
#pragma unroll
        for (int p = 0; p < 2; ++p) {
          float gate = acc[i * 4 + 2 * p][rr];
          float lin = acc[i * 4 + 2 * p + 1][rr];
          int col = ((n0 + wn) >> 1) + p * 16 + fr;
          ((u16*)out)[(size_t)gm * 2816 + col] = f2bf(gelu_f(gate) * lin);
        }
        continue;
      }
#pragma unroll
      for (int j = 0; j < 4; ++j) {
        int gn = n0 + wn + j * 16 + fr;
        float v = acc[i * 4 + j][rr];
        size_t oi = (size_t)gm * N + gn;
        if (MODE == 1) {
          float* po = blockIdx.z ? (float*)out2 : (float*)out;
          po[oi] = v;
        }
        if (MODE == 8) {
          int b = (int)(gm >> 10), l = (int)(gm & 1023), h = gn >> 6, e = gn & 63;
          ((u16*)out)[(((size_t)(b * 16 + h)) * 1024 + l) * 64 + e] = f2bf(v * alpha);
        }
        if (MODE == 11 || MODE == 14) {
          int b = (int)(gm >> 10), l = (int)(gm & 1023);
          int sec = gn >> 10, nn = gn & 1023, h = nn >> 6, e = nn & 63;
          if (sec == 0)
            ((u16*)out)[(((size_t)(b * 16 + h)) * 1024 + l) * 64 + e] = f2bf(v * alpha);
          else if (sec == 1)
            ((u16*)out2)[(((size_t)(b * 16 + h)) * 1056 + 30 + l) * 64 + e] = f2bf(v);
          else
            ((u16*)out3)[(((size_t)(b * 16 + h)) * 64 + e) * 1056 + 30 + l] = f2bf(v);
        }
      }
    }
  }
}

// ---------------------------------------------------------------------------
// Small bounds-checked GEMM (VGPR staging) for adapter matmuls.
// MODE 6: bf16 out gelu(acc + biasf[n])
// MODE 7: f32 out acc + biasf + res1 + res2 + res3
// ---------------------------------------------------------------------------
template <int MODE>
__global__ __launch_bounds__(256) void gemm_bt(
    const u16* __restrict__ A, const u16* __restrict__ Bt, void* __restrict__ out,
    const float* __restrict__ res1, const float* __restrict__ res2,
    const float* __restrict__ res3, const float* __restrict__ bias,
    int M, int N, int K,
    long Asb, long Bsb, long bsb, long r1sb, long r2sb, long r3sb, long osb) {
  const int BM = 128, BK = 32, LP = 40;
  __shared__ __align__(16) u16 As[BM * LP];
  __shared__ __align__(16) u16 Bs[BM * LP];

  const int t = threadIdx.x;
  const int m0 = blockIdx.y * BM;
  const int n0 = blockIdx.x * 128;
  const int bz = blockIdx.z;
  A += (size_t)bz * Asb;
  Bt += (size_t)bz * Bsb;

  f32x4 acc[16];
#pragma unroll
  for (int i = 0; i < 16; ++i) acc[i] = (f32x4){0.f, 0.f, 0.f, 0.f};
  const int wave = t >> 6, lane = t & 63;
  const int wm = (wave >> 1) * 64, wn = (wave & 1) * 64;
  const int fr = lane & 15, fq = lane >> 4;

  for (int k0 = 0; k0 < K; k0 += BK) {
#pragma unroll
    for (int i = 0; i < 2; ++i) {
      int idx = (i * 256 + t) * 8;
      int row = idx >> 5, col = idx & 31;
      *(uint4*)&As[row * LP + col] =
          *(const uint4*)(A + (size_t)(m0 + row) * K + k0 + col);
      uint4 bv = {0u, 0u, 0u, 0u};
      if (n0 + row < N) bv = *(const uint4*)(Bt + (size_t)(n0 + row) * K + k0 + col);
      *(uint4*)&Bs[row * LP + col] = bv;
    }
    __syncthreads();
    bf16x8 af[4], bfr[4];
#pragma unroll
    for (int i = 0; i < 4; ++i)
      af[i] = *(const bf16x8*)&As[(wm + i * 16 + fr) * LP + fq * 8];
#pragma unroll
    for (int j = 0; j < 4; ++j)
      bfr[j] = *(const bf16x8*)&Bs[(wn + j * 16 + fr) * LP + fq * 8];
#pragma unroll
    for (int i = 0; i < 4; ++i)
#pragma unroll
      for (int j = 0; j < 4; ++j)
        acc[i * 4 + j] = __builtin_amdgcn_mfma_f32_16x16x32_bf16(
            af[i], bfr[j], acc[i * 4 + j], 0, 0, 0);
    __syncthreads();
  }

#pragma unroll
  for (int i = 0; i < 4; ++i) {
#pragma unroll
    for (int rr = 0; rr < 4; ++rr) {
      long gm = (long)m0 + wm + i * 16 + fq * 4 + rr;
#pragma unroll
      for (int j = 0; j < 4; ++j) {
        int gn = n0 + wn + j * 16 + fr;
        if (gn >= N) continue;
        float v = acc[i * 4 + j][rr];
        size_t oi = (size_t)bz * osb + (size_t)gm * N + gn;
        size_t ri = (size_t)gm * N + gn;
        if (MODE == 6) ((u16*)out)[oi] = f2bf(gelu_f(v + bias[(size_t)bz * bsb + gn]));
        if (MODE == 7)
          ((float*)out)[oi] = v + bias[(size_t)bz * bsb + gn] +
                              res1[(size_t)bz * r1sb + ri] +
                              res2[(size_t)bz * r2sb + ri] +
                              res3[(size_t)bz * r3sb + ri];
      }
    }
  }
}

// ---------------------------------------------------------------------------
// Barrier-free MFMA flash attention, NO-MAX softmax (scores O(+-6); masked
// lanes s=-3e38 -> exp=0). Row-sum l via ones-B MFMA. 32 Q-ROWS PER WAVE:
// two 16-row Q sub-tiles share each K/V fragment load, HALVING the VMEM
// return bytes per unit work -- the measured bottleneck (R5: -74 us total,
// confirmed). Block = (b,h,128 q-rows), 4 waves x 32. Grid 512 = 2/CU.
// XCD swizzle: 64 wg/XCD -> K/V of 8 (b,h) pairs per XCD (2.2 MB < L2).
// Q [B,H,1024,64] bf16 (pre-scaled). K [B,H,1056,64]. Vt [B,H,64,1056].
// ---------------------------------------------------------------------------
template <bool IS_SELF>
__global__ __launch_bounds__(256) void fattn_k(
    const u16* __restrict__ Qg, const u16* __restrict__ Kg,
    const u16* __restrict__ Vtg, const float* __restrict__ bias_tab,
    u16* __restrict__ Out) {
  const int L = 1024, P = 30, KC = 1056;
  // XCD swizzle: 512 blocks, 8 XCDs (round-robin flat%8), 64 wg per XCD.
  const int flat = blockIdx.x;
  const int wg = (flat & 7) * 64 + (flat >> 3);
  const int q0b = (wg & 7) * 128;
  const int h = (wg >> 3) & 15, b = wg >> 7;
  const int t = threadIdx.x, wave = t >> 6, lane = t & 63;
  const int fr = lane & 15, fq = lane >> 4;
  const int q0w = q0b + wave * 32;

  __shared__ float bTs[IS_SELF ? 1024 : 4];
  __shared__ __align__(16) u16 Ps[4][32][40];

  if (IS_SELF) {
#pragma unroll
    for (int i = 0; i < 4; ++i) bTs[t + i * 256] = bias_tab[h * 1024 + t + i * 256];
    __syncthreads();  // once per kernel
  }

  // Q fragments: two 16-row sub-tiles (A: rows q0w.., B: rows q0w+16..)
  const u16* qptr = Qg + (((size_t)(b * 16 + h)) * L + q0w + fr) * 64 + fq * 8;
  bf16x8 qa0 = *(const bf16x8*)qptr;
  bf16x8 qa1 = *(const bf16x8*)(qptr + 32);
  bf16x8 qb0 = *(const bf16x8*)(qptr + 16 * 64);
  bf16x8 qb1 = *(const bf16x8*)(qptr + 16 * 64 + 32);

  f32x4 oA[4], oB[4];
#pragma unroll
  for (int i = 0; i < 4; ++i) {
    oA[i] = (f32x4){0.f, 0.f, 0.f, 0.f};
    oB[i] = (f32x4){0.f, 0.f, 0.f, 0.f};
  }
  f32x4 olA = (f32x4){0.f, 0.f, 0.f, 0.f};
  f32x4 olB = (f32x4){0.f, 0.f, 0.f, 0.f};
  bf16x8 ones;
  {
    u16 one = 0x3F80;  // bf16 1.0
#pragma unroll
    for (int i = 0; i < 8; ++i) ((u16*)&ones)[i] = one;
  }

  const int nk = IS_SELF ? (P + q0b + 128) : (P + L);
  const int nch = (nk + 31) >> 5;
  // per-lane fragment base pointers (identical across the block's 4 waves)
  const u16* kp = Kg + ((size_t)(b * 16 + h)) * KC * 64 + (size_t)fr * 64 + fq * 8;
  const u16* vp = Vtg + ((size_t)(b * 16 + h)) * 64 * KC + (size_t)fr * KC + fq * 8;

  bf16x8 kf0 = *(const bf16x8*)(kp + 0);
  bf16x8 kf1 = *(const bf16x8*)(kp + 32);
  bf16x8 kf2 = *(const bf16x8*)(kp + 16 * 64);
  bf16x8 kf3 = *(const bf16x8*)(kp + 16 * 64 + 32);

  // bias+mask+exp+Ps-store for one 16-row score tile; rb = row base (0/16)
  auto smax = [&](f32x4* s, int k0, int qoff, int rb) {
    const bool full = IS_SELF ? (k0 >= 32 && k0 + 31 - P <= qoff)
                              : (k0 + 31 < P + L);
    if (full) {
      if (IS_SELF) {
#pragma unroll
        for (int reg = 0; reg < 4; ++reg) {
          const int qq = qoff + fq * 4 + reg;
          s[0][reg] += bTs[qq - (k0 + fr - P)];
          s[1][reg] += bTs[qq - (k0 + 16 + fr - P)];
        }
      }
    } else {
#pragma unroll
      for (int reg = 0; reg < 4; ++reg) {
        const int qq = qoff + fq * 4 + reg;
#pragma unroll
        for (int t2 = 0; t2 < 2; ++t2) {
          const int kvi = k0 + t2 * 16 + fr;
          float sv = s[t2][reg];
          if (IS_SELF) {
            const int lk = kvi - P;
            if (lk >= 0) {
              if (lk <= qq) sv += bTs[qq - lk];
              else sv = -3.0e38f;
            }
          } else {
            if (kvi >= P + L) sv = -3.0e38f;
          }
          s[t2][reg] = sv;
        }
      }
    }
    // no-max softmax: p = exp(s); masked s=-3e38 -> p=0
#pragma unroll
    for (int reg = 0; reg < 4; ++reg) {
      Ps[wave][rb + fq * 4 + reg][fr] = f2bf_fast(__expf(s[0][reg]));
      Ps[wave][rb + fq * 4 + reg][16 + fr] = f2bf_fast(__expf(s[1][reg]));
    }
  };

  for (int ch = 0; ch < nch; ++ch) {
    const int k0 = ch * 32;
    bf16x8 vf0 = *(const bf16x8*)(vp + 0 * 16 * KC + k0);
    bf16x8 vf1 = *(const bf16x8*)(vp + 1 * 16 * KC + k0);
    bf16x8 vf2 = *(const bf16x8*)(vp + 2 * 16 * KC + k0);
    bf16x8 vf3 = *(const bf16x8*)(vp + 3 * 16 * KC + k0);
    const int k0n = (ch + 1 < nch) ? (k0 + 32) : 0;
    bf16x8 kn0 = *(const bf16x8*)(kp + (size_t)k0n * 64);
    bf16x8 kn1 = *(const bf16x8*)(kp + (size_t)k0n * 64 + 32);
    bf16x8 kn2 = *(const bf16x8*)(kp + (size_t)(k0n + 16) * 64);
    bf16x8 kn3 = *(const bf16x8*)(kp + (size_t)(k0n + 16) * 64 + 32);

    f32x4 sA[2], sB[2];
    sA[0] = (f32x4){0.f, 0.f, 0.f, 0.f};
    sA[1] = (f32x4){0.f, 0.f, 0.f, 0.f};
    sB[0] = (f32x4){0.f, 0.f, 0.f, 0.f};
    sB[1] = (f32x4){0.f, 0.f, 0.f, 0.f};
    sA[0] = __builtin_amdgcn_mfma_f32_16x16x32_bf16(qa0, kf0, sA[0], 0, 0, 0);
    sA[0] = __builtin_amdgcn_mfma_f32_16x16x32_bf16(qa1, kf1, sA[0], 0, 0, 0);
    sA[1] = __builtin_amdgcn_mfma_f32_16x16x32_bf16(qa0, kf2, sA[1], 0, 0, 0);
    sA[1] = __builtin_amdgcn_mfma_f32_16x16x32_bf16(qa1, kf3, sA[1], 0, 0, 0);
    sB[0] = __builtin_amdgcn_mfma_f32_16x16x32_bf16(qb0, kf0, sB[0], 0, 0, 0);
    sB[0] = __builtin_amdgcn_mfma_f32_16x16x32_bf16(qb1, kf1, sB[0], 0, 0, 0);
    sB[1] = __builtin_amdgcn_mfma_f32_16x16x32_bf16(qb0, kf2, sB[1], 0, 0, 0);
    sB[1] = __builtin_amdgcn_mfma_f32_16x16x32_bf16(qb1, kf3, sB[1], 0, 0, 0);

    smax(sA, k0, q0w, 0);
    smax(sB, k0, q0w + 16, 16);
    __asm__ volatile("s_waitcnt lgkmcnt(0)" ::: "memory");
    bf16x8 paA = *(const bf16x8*)&Ps[wave][fr][fq * 8];
    bf16x8 paB = *(const bf16x8*)&Ps[wave][16 + fr][fq * 8];

    // P @ V : per sub-tile 4 dim-tiles + 1 ones-tile (row-sum l)
    oA[0] = __builtin_amdgcn_mfma_f32_16x16x32_bf16(paA, vf0, oA[0], 0, 0, 0);
    oA[1] = __builtin_amdgcn_mfma_f32_16x16x32_bf16(paA, vf1, oA[1], 0, 0, 0);
    oA[2] = __builtin_amdgcn_mfma_f32_16x16x32_bf16(paA, vf2, oA[2], 0, 0, 0);
    oA[3] = __builtin_amdgcn_mfma_f32_16x16x32_bf16(paA, vf3, oA[3], 0, 0, 0);
    olA   = __builtin_amdgcn_mfma_f32_16x16x32_bf16(paA, ones, olA, 0, 0, 0);
    oB[0] = __builtin_amdgcn_mfma_f32_16x16x32_bf16(paB, vf0, oB[0], 0, 0, 0);
    oB[1] = __builtin_amdgcn_mfma_f32_16x16x32_bf16(paB, vf1, oB[1], 0, 0, 0);
    oB[2] = __builtin_amdgcn_mfma_f32_16x16x32_bf16(paB, vf2, oB[2], 0, 0, 0);
    oB[3] = __builtin_amdgcn_mfma_f32_16x16x32_bf16(paB, vf3, oB[3], 0, 0, 0);
    olB   = __builtin_amdgcn_mfma_f32_16x16x32_bf16(paB, ones, olB, 0, 0, 0);

    kf0 = kn0; kf1 = kn1; kf2 = kn2; kf3 = kn3;
  }

  float invA[4], invB[4];
#pragma unroll
  for (int reg = 0; reg < 4; ++reg) {
    invA[reg] = 1.0f / olA[reg];
    invB[reg] = 1.0f / olB[reg];
  }
#pragma unroll
  for (int dt = 0; dt < 4; ++dt) {
#pragma unroll
    for (int reg = 0; reg < 4; ++reg) {
      size_t rowA = (size_t)(b * L + q0w + fq * 4 + reg);
      Out[(rowA * 16 + h) * 64 + dt * 16 + fr] = f2bf(oA[dt][reg] * invA[reg]);
      size_t rowB = rowA + 16;
      Out[(rowB * 16 + h) * 64 + dt * 16 + fr] = f2bf(oB[dt][reg] * invB[reg]);
    }
  }
}

// ---------------------------------------------------------------------------
extern "C" void kernel_launch(void* const* d_in, const int* in_sizes, int n_in,
                              void* d_out, int out_size, void* d_ws, size_t ws_size,
                              hipStream_t stream) {
  const int B = 4, L = 1024, D = 1024, H = 16, F = 2816, AD = 64;
  const int M = B * L;  // 4096
  const int KC = 1056;

  const float* inputs  = (const float*)d_in[0];
  const float* encoded = (const float*)d_in[1];
  const float* a_wd    = (const float*)d_in[2];
  const float* a_wu    = (const float*)d_in[3];
  const float* a_bd    = (const float*)d_in[4];
  const float* a_bu    = (const float*)d_in[5];
  const float* pK      = (const float*)d_in[6];
  const float* pV      = (const float*)d_in[7];
  const float* ln1     = (const float*)d_in[8];
  const float* ln2     = (const float*)d_in[9];
  const float* ln3     = (const float*)d_in[10];
  const float* sa_wq   = (const float*)d_in[11];
  const float* sa_wk   = (const float*)d_in[12];
  const float* sa_wv   = (const float*)d_in[13];
  const float* sa_wo   = (const float*)d_in[14];
  const float* ca_wq   = (const float*)d_in[15];
  const float* ca_wk   = (const float*)d_in[16];
  const float* ca_wv   = (const float*)d_in[17];
  const float* ca_wo   = (const float*)d_in[18];
  const float* relpos  = (const float*)d_in[19];
  const float* wi0     = (const float*)d_in[20];
  const float* wi1     = (const float*)d_in[21];
  const float* wom     = (const float*)d_in[22];

  char* w = (char*)d_ws;
  size_t used = 0;
  auto alloc = [&](size_t bytes) {
    char* p = w + used;
    used += (bytes + 255) & ~(size_t)255;
    return p;
  };
  // --- weights (persistent) ---
  // The first five live CONTIGUOUSLY (8 x 1M u16) so one batched transpose
  // (z=8) fills them: [wq|wk|wv | wo | cq | ck|cv | co].
  u16* wqkvT  = (u16*)alloc((size_t)3072 * 1024 * 2);  // [wq;wk;wv]^T
  u16* woT    = (u16*)alloc((size_t)D * 1024 * 2);
  u16* cqT    = (u16*)alloc((size_t)D * 1024 * 2);     // cqkvT base (cq;ck;cv)
  u16* ckvT   = (u16*)alloc((size_t)2048 * 1024 * 2);  // [ck;cv]^T
  u16* coT    = (u16*)alloc((size_t)D * 1024 * 2);
  u16* wi01T  = (u16*)alloc((size_t)5632 * 1024 * 2);  // 16-col-block interleaved
  u16* womT   = (u16*)alloc((size_t)D * F * 2);
  u16* wdT    = (u16*)alloc((size_t)B * AD * D * 2);
  u16* wuT    = (u16*)alloc((size_t)B * D * AD * 2);
  float* bT   = (float*)alloc((size_t)H * 1024 * 4);
  // --- activations ---
  // region A (24 MiB): enc16 + xn + lz
  u16* enc16  = (u16*)alloc((size_t)M * D * 2);            // 8 MiB
  u16* xn     = (u16*)alloc((size_t)M * D * 2);            // 8 MiB
  u16* lz     = (u16*)alloc((size_t)M * D * 2);            // 8 MiB
  // region B (48.5 MiB): Kc + Vtc + qh + ao + xf
  u16* Kc     = (u16*)alloc((size_t)B * H * KC * 64 * 2);  // 8.25 MiB
  u16* Vtc    = (u16*)alloc((size_t)B * H * 64 * KC * 2);  // 8.25 MiB
  u16* qh     = (u16*)alloc((size_t)B * H * L * 64 * 2);   // 8 MiB
  u16* ao     = (u16*)alloc((size_t)M * D * 2);            // 8 MiB
  float* xf   = (float*)alloc((size_t)M * D * 4);          // 16 MiB
  float* yf   = (float*)alloc((size_t)M * D * 4);          // 16 MiB, dedicated
  u16* az1    = (u16*)alloc((size_t)B * 1024 * AD * 2);    // 0.5 MiB, dedicated
  // aliases (lifetimes disjoint; see ordering below):
  // wo-proj split-K partials: p0/q0 @ Kc (16 MiB over Kc+Vtc, dead post-fattn);
  //   p1 @ xf, q1 @ yf (combined in-place by rmsnorm_sum_k).
  float* pk0  = (float*)Kc;
  // MLP: g @ Kc (23.1 MiB over Kc+Vtc+qh, q0 dead); down-proj partials:
  //   zf0 @ enc16 (16 MiB over enc16+xn, dead), zf1 @ ao (16 MiB over ao+xf/2).
  u16* g      = Kc;
  float* zf0  = (float*)enc16;
  float* zf1  = (float*)ao;
  if (used > ws_size) return;

  dim3 tb(256);
  // Batched weight transposes (launch-count reduction: 15 -> 7 preamble).
  TSrc8 s8;
  s8.p[0] = sa_wq; s8.p[1] = sa_wk; s8.p[2] = sa_wv; s8.p[3] = sa_wo;
  s8.p[4] = ca_wq; s8.p[5] = ca_wk; s8.p[6] = ca_wv; s8.p[7] = ca_wo;
  transpose8_k<<<dim3(32, 32, 8), tb, 0, stream>>>(
      s8, wqkvT, 1024, 1024, (long)1024 * 1024, 1, 0);
  TSrc8 swi;
  swi.p[0] = wi0; swi.p[1] = wi1;
  for (int i = 2; i < 8; ++i) swi.p[i] = wi0;
  transpose8_k<<<dim3(88, 32, 2), tb, 0, stream>>>(
      swi, wi01T, 1024, 2816, 0, 2, 1);  // 16-col-block interleave, roff=z
  transpose_k<<<dim3(32, 88, 1), tb, 0, stream>>>(
      wom, womT, 2816, 1024, 0, 0, 1, 0);
  transpose_k<<<dim3(2, 32, B), tb, 0, stream>>>(
      a_wd, wdT, D, AD, (long)D * AD, (long)D * AD, 1, 0);
  transpose_k<<<dim3(32, 2, B), tb, 0, stream>>>(
      a_wu, wuT, AD, D, (long)AD * D, (long)AD * D, 1, 0);
  bias_tab_k<<<dim3(64), tb, 0, stream>>>(relpos, bT);
  cast_bf16_k<<<dim3(M * D / 4 / 256), tb, 0, stream>>>(encoded, enc16, M * D / 4);

  // ---- self attention ----
  rmsnorm_k<<<dim3(M), tb, 0, stream>>>(inputs, ln1, xn);
  gemm97<11><<<dim3(24, 32), tb, 0, stream>>>(
      xn, nullptr, wqkvT, qh, Kc, Vtc, M, 3072, 1024, 1024, 0.125f);
  prefix_fill_k<<<dim3(512), tb, 0, stream>>>(pK, pV, Kc, Vtc, 0);
  fattn_k<true><<<dim3(512), tb, 0, stream>>>(qh, Kc, Vtc, bT, ao);
  // split-K wo-proj: partials p0 @ Kc (K/V dead), p1 @ xf; combine fused
  // into rmsnorm_sum (writes xn = rmsnorm(xf_sum)*ln2 and xf = sum).
  gemm97<1><<<dim3(8, 32, 2), tb, 0, stream>>>(
      ao, nullptr, woT, pk0, xf, nullptr, M, 1024, 1024, 512, 1.f);
  rmsnorm_sum_k<<<dim3(M), tb, 0, stream>>>(pk0, xf, inputs, ln2, xn, xf);
  // ---- cross attention ----
  // merged Q+KV projection: sec0 A=xn (Q *alpha), sec1/2 A2=enc16 (K,V).
  gemm97<14><<<dim3(24, 32), tb, 0, stream>>>(
      xn, enc16, cqT, qh, Kc, Vtc, M, 3072, 1024, 1024, 0.125f);
  prefix_fill_k<<<dim3(512), tb, 0, stream>>>(pK, pV, Kc, Vtc, 1);
  fattn_k<false><<<dim3(512), tb, 0, stream>>>(qh, Kc, Vtc, nullptr, ao);
  gemm97<1><<<dim3(8, 32, 2), tb, 0, stream>>>(
      ao, nullptr, coT, pk0, yf, nullptr, M, 1024, 1024, 512, 1.f);
  rmsnorm_sum_k<<<dim3(M), tb, 0, stream>>>(pk0, yf, xf, ln3, lz, yf);
  // ---- MLP + adapter ----
  //  1) az1 = gelu(lz@wd + bd)            (dedicated az1)
  //  2) g = fused-gelu up-proj (MODE 13)  (writes Kc..qh; q0/K/V dead)
  //  3) zf0/zf1 = split-K halves of g@wom (zf0 @ enc16.., zf1 @ ao.. -- dead)
  //  4) out = az1@wu + bu + zf0 + zf1 + yf
  gemm_bt<6><<<dim3(1, 8, B), tb, 0, stream>>>(
      lz, wdT, az1, nullptr, nullptr, nullptr, a_bd, 1024, AD, D,
      (long)1024 * D, (long)AD * D, (long)AD, 0, 0, 0, (long)1024 * AD);
  gemm97<13><<<dim3(44, 32), tb, 0, stream>>>(
      lz, nullptr, wi01T, g, nullptr, nullptr, M, 5632, 1024, 1024, 1.f);
  gemm97<1><<<dim3(8, 32, 2), tb, 0, stream>>>(
      g, nullptr, womT, zf0, zf1, nullptr, M, 1024, 2816, 1408, 1.f);
  gemm_bt<7><<<dim3(8, 8, B), tb, 0, stream>>>(
      az1, wuT, d_out, zf0, zf1, yf, a_bu, 1024, 1024, AD,
      (long)1024 * AD, (long)D * AD, (long)1024, (long)1024 * 1024,
      (long)1024 * 1024, (long)1024 * 1024, (long)1024 * 1024);
  (void)in_sizes; (void)n_in; (void)out_size;
}

// Round 10
// 696.700 us; speedup vs baseline: 1.0245x; 1.0245x over previous
//
#include <hip/hip_runtime.h>

typedef unsigned short u16;
typedef __attribute__((ext_vector_type(8))) __bf16 bf16x8;
typedef __attribute__((ext_vector_type(4))) float f32x4;

__device__ __forceinline__ float bf2f(u16 u) {
  union { unsigned int i; float f; } v; v.i = ((unsigned int)u) << 16; return v.f;
}
__device__ __forceinline__ u16 f2bf(float f) {
  unsigned int x = __float_as_uint(f);
  unsigned int r = (x + 0x7fffu + ((x >> 16) & 1u)) >> 16;
  return (u16)r;
}
__device__ __forceinline__ u16 f2bf_fast(float f) {
  return (u16)((__float_as_uint(f) + 0x8000u) >> 16);
}
__device__ __forceinline__ float gelu_f(float x) {
  float u = 0.7978845608028654f * (x + 0.044715f * x * x * x);
  float t = 1.0f - 2.0f / (__expf(2.0f * u) + 1.0f);
  return 0.5f * x * (1.0f + t);
}
// async global->LDS, 16B per lane. l must be wave-uniform base.
__device__ __forceinline__ void gl_lds16(const u16* g, u16* l) {
  __builtin_amdgcn_global_load_lds(
      (const __attribute__((address_space(1))) unsigned int*)g,
      (__attribute__((address_space(3))) unsigned int*)l, 16, 0, 0);
}

// ---------------------------------------------------------------------------
__global__ __launch_bounds__(256) void cast_bf16_k(const float* __restrict__ in,
                                                   u16* __restrict__ out, int n4) {
  int i = blockIdx.x * 256 + threadIdx.x;
  if (i >= n4) return;
  float4 v = ((const float4*)in)[i];
  ushort4 o;
  o.x = f2bf(v.x); o.y = f2bf(v.y); o.z = f2bf(v.z); o.w = f2bf(v.w);
  ((ushort4*)out)[i] = o;
}

// ---------------------------------------------------------------------------
// Universal output-row mapping: row' = ((cc>>4)*rs + roff)*16 + (cc&15).
// rs=1,roff=0 -> row'=cc (plain). rs=2,roff=s -> 16-col-block interleave
// (for wi0/wi1 -> wi01T pairing consumed by gemm97 MODE 13).
// ---------------------------------------------------------------------------
__global__ __launch_bounds__(256) void transpose_k(
    const float* __restrict__ in, u16* __restrict__ out, int R, int C,
    long isb, long osb, int rs, int roff) {
  __shared__ u16 tile[32][33];
  in += (size_t)blockIdx.z * isb;
  out += (size_t)blockIdx.z * osb;
  int c0 = blockIdx.x * 32, r0 = blockIdx.y * 32;
  int tx = threadIdx.x & 31, ty = threadIdx.x >> 5;
#pragma unroll
  for (int i = 0; i < 4; ++i) {
    int rr = r0 + ty + i * 8;
    if (rr < R && c0 + tx < C) tile[ty + i * 8][tx] = f2bf(in[(size_t)rr * C + c0 + tx]);
  }
  __syncthreads();
#pragma unroll
  for (int i = 0; i < 4; ++i) {
    int cc = c0 + ty + i * 8;
    if (cc < C && r0 + tx < R) {
      int orow = (((cc >> 4) * rs + roff) << 4) + (cc & 15);
      out[(size_t)orow * R + r0 + tx] = tile[tx][ty + i * 8];
    }
  }
}

// ---------------------------------------------------------------------------
// Batched transpose: z selects source pointer from a by-value struct; dst is
// out + z*zstride. roffz: roff = z (wi0/wi1 interleave) else 0.
// ---------------------------------------------------------------------------
struct TSrc8 { const float* p[8]; };
__global__ __launch_bounds__(256) void transpose8_k(
    TSrc8 srcs, u16* __restrict__ out, int R, int C,
    long zstride, int rs, int roffz) {
  __shared__ u16 tile[32][33];
  const float* __restrict__ in = srcs.p[blockIdx.z];
  out += (size_t)blockIdx.z * zstride;
  const int roff = roffz ? blockIdx.z : 0;
  int c0 = blockIdx.x * 32, r0 = blockIdx.y * 32;
  int tx = threadIdx.x & 31, ty = threadIdx.x >> 5;
#pragma unroll
  for (int i = 0; i < 4; ++i) {
    int rr = r0 + ty + i * 8;
    if (rr < R && c0 + tx < C) tile[ty + i * 8][tx] = f2bf(in[(size_t)rr * C + c0 + tx]);
  }
  __syncthreads();
#pragma unroll
  for (int i = 0; i < 4; ++i) {
    int cc = c0 + ty + i * 8;
    if (cc < C && r0 + tx < R) {
      int orow = (((cc >> 4) * rs + roff) << 4) + (cc & 15);
      out[(size_t)orow * R + r0 + tx] = tile[tx][ty + i * 8];
    }
  }
}

// ---------------------------------------------------------------------------
__global__ __launch_bounds__(256) void bias_tab_k(const float* __restrict__ relpos,
                                                  float* __restrict__ tab) {
  int idx = blockIdx.x * 256 + threadIdx.x;  // 16*1024
  int h = idx >> 10, d = idx & 1023;
  int bucket;
  if (d < 16) bucket = d;
  else {
    int lb = 16 + (int)(logf((float)d * (1.0f / 16.0f)) * (16.0f / logf(8.0f)));
    bucket = lb < 31 ? lb : 31;
  }
  tab[idx] = relpos[h * 32 + bucket];
}

// ---------------------------------------------------------------------------
__global__ __launch_bounds__(256) void prefix_fill_k(
    const float* __restrict__ pK, const float* __restrict__ pV,
    u16* __restrict__ Kd, u16* __restrict__ Vtd, int sSel) {
  int idx = blockIdx.x * 256 + threadIdx.x;  // B*H*32*64 = 131072
  int e = idx & 63, p = (idx >> 6) & 31, h = (idx >> 11) & 15, b = idx >> 15;
  int key = (p < 30) ? p : (1024 + p);  // pads -> 1054,1055
  float kv = 0.f, vv = 0.f;
  if (p < 30) {
    size_t src = ((((size_t)(b * 2 + sSel)) * 30 + p) * 16 + h) * 64 + e;
    kv = pK[src]; vv = pV[src];
  }
  Kd[(((size_t)(b * 16 + h)) * 1056 + key) * 64 + e] = f2bf(kv);
  Vtd[(((size_t)(b * 16 + h)) * 64 + e) * 1056 + key] = f2bf(vv);
}

// ---------------------------------------------------------------------------
__global__ __launch_bounds__(256) void rmsnorm_k(const float* __restrict__ in,
                                                 const float* __restrict__ scale,
                                                 u16* __restrict__ out) {
  const int D = 1024;
  size_t base = (size_t)blockIdx.x * D;
  int t = threadIdx.x;
  float x[4];
#pragma unroll
  for (int i = 0; i < 4; ++i) x[i] = in[base + t + i * 256];
  float s = x[0] * x[0] + x[1] * x[1] + x[2] * x[2] + x[3] * x[3];
#pragma unroll
  for (int off = 1; off < 64; off <<= 1) s += __shfl_xor(s, off, 64);
  __shared__ float ws4[4];
  if ((t & 63) == 0) ws4[t >> 6] = s;
  __syncthreads();
  float tot = ws4[0] + ws4[1] + ws4[2] + ws4[3];
  float r = rsqrtf(tot * (1.0f / D) + 1e-6f);
#pragma unroll
  for (int i = 0; i < 4; ++i) {
    int c = t + i * 256;
    out[base + c] = f2bf(x[i] * r * scale[c]);
  }
}

// ---------------------------------------------------------------------------
// Split-K combine fused into rmsnorm: x = in0 + in1 + res; outs = x (f32,
// may alias in1 -- elementwise same-index read-then-write is safe);
// outn = rmsnorm(x)*scale (bf16).
// ---------------------------------------------------------------------------
__global__ __launch_bounds__(256) void rmsnorm_sum_k(
    const float* __restrict__ in0, const float* __restrict__ in1,
    const float* __restrict__ res, const float* __restrict__ scale,
    u16* __restrict__ outn, float* __restrict__ outs) {
  const int D = 1024;
  size_t base = (size_t)blockIdx.x * D;
  int t = threadIdx.x;
  float x[4];
#pragma unroll
  for (int i = 0; i < 4; ++i) {
    int c = t + i * 256;
    x[i] = in0[base + c] + in1[base + c] + res[base + c];
    outs[base + c] = x[i];
  }
  float s = x[0] * x[0] + x[1] * x[1] + x[2] * x[2] + x[3] * x[3];
#pragma unroll
  for (int off = 1; off < 64; off <<= 1) s += __shfl_xor(s, off, 64);
  __shared__ float ws4[4];
  if ((t & 63) == 0) ws4[t >> 6] = s;
  __syncthreads();
  float tot = ws4[0] + ws4[1] + ws4[2] + ws4[3];
  float r = rsqrtf(tot * (1.0f / D) + 1e-6f);
#pragma unroll
  for (int i = 0; i < 4; ++i) {
    int c = t + i * 256;
    outn[base + c] = f2bf(x[i] * r * scale[c]);
  }
}

// ---------------------------------------------------------------------------
// m97-style MFMA GEMM: C[M][N] = A[M][K-stride] @ Bt[N][K-stride]^T.
// 128x128 tile, BK=32, global_load_lds width-16 staging, unpadded LDS.
// K = row stride of A/Bt; Ks = K-loop length (== K except split-K);
// blockIdx.z selects the K-slice (kbase = z*Ks) for MODE 1.
// Bijective XCD swizzle ONLY for MODE 1 (narrow N; wide-N measured harmful
// in R7: contiguous-chunk swizzle streams the whole B panel per XCD).
// Epilogue MODE:
//  1: split-K f32 partial (z=0 -> out, z=1 -> out2)
//  8: Q scatter (*alpha)
//  11: QKV scatter (sec0 Q *alpha; sec1 K +30; sec2 Vt +30)
//  13: fused gelu-gate, 16-col-block interleaved wi01T: j-tiles (2p,2p+1)
//      are (gate,lin) for the same 16 cols -> out=gelu(gate)*lin, no shfl.
//  14: like 11 but A is per-section: sec0 reads A (xn), sec1/2 read A2
//      (enc16) -- merged cross Q+KV projection.
// Scatter: Q [B,H,1024,64] *alpha; K [B,H,1056,64] +30; Vt [B,H,64,1056] +30
// ---------------------------------------------------------------------------
template <int MODE>
__global__ __launch_bounds__(256) void gemm97(
    const u16* __restrict__ A, const u16* __restrict__ A2,
    const u16* __restrict__ Bt, void* __restrict__ out,
    void* __restrict__ out2, void* __restrict__ out3,
    int M, int N, int K, int Ks, float alpha) {
  const int BK = 32;
  __shared__ __align__(16) u16 As[128 * 32];
  __shared__ __align__(16) u16 Bs[128 * 32];

  const int t = threadIdx.x;
  const int wave = t >> 6, lane = t & 63;
  int m0, n0;
  if (MODE == 1) {
    // XCD-aware bijective swizzle: contiguous chunk of wg per XCD.
    int wgid = blockIdx.y * gridDim.x + blockIdx.x;
    const int cpx = (gridDim.x * gridDim.y) >> 3;
    wgid = (wgid & 7) * cpx + (wgid >> 3);
    m0 = (wgid / gridDim.x) * 128;
    n0 = (wgid % gridDim.x) * 128;
  } else {
    m0 = blockIdx.y * 128;
    n0 = blockIdx.x * 128;
  }
  const int kbase = blockIdx.z * Ks;
  const int fr = lane & 15, fq = lane >> 4;
  const int wm = (wave >> 1) * 64, wn = (wave & 1) * 64;

  const u16* Ause = (MODE == 14 && n0 >= 1024) ? A2 : A;
  const int srow = wave * 32 + (lane >> 2);
  const int scol = (lane & 3) * 8;
  const u16* ag0 = Ause + (size_t)(m0 + srow) * K + kbase + scol;
  const u16* ag1 = ag0 + (size_t)16 * K;
  const u16* bg0 = Bt + (size_t)(n0 + srow) * K + kbase + scol;
  const u16* bg1 = bg0 + (size_t)16 * K;
  u16* al0 = &As[(wave * 32) * 32];
  u16* al1 = &As[(wave * 32 + 16) * 32];
  u16* bl0 = &Bs[(wave * 32) * 32];
  u16* bl1 = &Bs[(wave * 32 + 16) * 32];

  f32x4 acc[16];
#pragma unroll
  for (int i = 0; i < 16; ++i) acc[i] = (f32x4){0.f, 0.f, 0.f, 0.f};

  for (int k0 = 0; k0 < Ks; k0 += BK) {
    gl_lds16(ag0 + k0, al0);
    gl_lds16(ag1 + k0, al1);
    gl_lds16(bg0 + k0, bl0);
    gl_lds16(bg1 + k0, bl1);
    __syncthreads();
    bf16x8 af[4], bf[4];
#pragma unroll
    for (int i = 0; i < 4; ++i)
      af[i] = *(const bf16x8*)&As[(wm + i * 16 + fr) * 32 + fq * 8];
#pragma unroll
    for (int j = 0; j < 4; ++j)
      bf[j] = *(const bf16x8*)&Bs[(wn + j * 16 + fr) * 32 + fq * 8];
#pragma unroll
    for (int i = 0; i < 4; ++i)
#pragma unroll
      for (int j = 0; j < 4; ++j)
        acc[i * 4 + j] = __builtin_amdgcn_mfma_f32_16x16x32_bf16(
            af[i], bf[j], acc[i * 4 + j], 0, 0, 0);
    __syncthreads();
  }

  // epilogue: D row = fq*4 + reg, col = fr
#pragma unroll
  for (int i = 0; i < 4; ++i) {
#pragma unroll
    for (int rr = 0; rr < 4; ++rr) {
      long gm = (long)m0 + wm + i * 16 + fq * 4 + rr;
      if (MODE == 13) {
#pragma unroll
        for (int p = 0; p < 2; ++p) {
          float gate = acc[i * 4 + 2 * p][rr];
          float lin = acc[i * 4 + 2 * p + 1][rr];
          int col = ((n0 + wn) >> 1) + p * 16 + fr;
          ((u16*)out)[(size_t)gm * 2816 + col] = f2bf(gelu_f(gate) * lin);
        }
        continue;
      }
#pragma unroll
      for (int j = 0; j < 4; ++j) {
        int gn = n0 + wn + j * 16 + fr;
        float v = acc[i * 4 + j][rr];
        size_t oi = (size_t)gm * N + gn;
        if (MODE == 1) {
          float* po = blockIdx.z ? (float*)out2 : (float*)out;
          po[oi] = v;
        }
        if (MODE == 8) {
          int b = (int)(gm >> 10), l = (int)(gm & 1023), h = gn >> 6, e = gn & 63;
          ((u16*)out)[(((size_t)(b * 16 + h)) * 1024 + l) * 64 + e] = f2bf(v * alpha);
        }
        if (MODE == 11 || MODE == 14) {
          int b = (int)(gm >> 10), l = (int)(gm & 1023);
          int sec = gn >> 10, nn = gn & 1023, h = nn >> 6, e = nn & 63;
          if (sec == 0)
            ((u16*)out)[(((size_t)(b * 16 + h)) * 1024 + l) * 64 + e] = f2bf(v * alpha);
          else if (sec == 1)
            ((u16*)out2)[(((size_t)(b * 16 + h)) * 1056 + 30 + l) * 64 + e] = f2bf(v);
          else
            ((u16*)out3)[(((size_t)(b * 16 + h)) * 64 + e) * 1056 + 30 + l] = f2bf(v);
        }
      }
    }
  }
}

// ---------------------------------------------------------------------------
// Small bounds-checked GEMM (VGPR staging) for adapter matmuls.
// MODE 6: bf16 out gelu(acc + biasf[n])
// MODE 7: f32 out acc + biasf + res1 + res2 + res3
// ---------------------------------------------------------------------------
template <int MODE>
__global__ __launch_bounds__(256) void gemm_bt(
    const u16* __restrict__ A, const u16* __restrict__ Bt, void* __restrict__ out,
    const float* __restrict__ res1, const float* __restrict__ res2,
    const float* __restrict__ res3, const float* __restrict__ bias,
    int M, int N, int K,
    long Asb, long Bsb, long bsb, long r1sb, long r2sb, long r3sb, long osb) {
  const int BM = 128, BK = 32, LP = 40;
  __shared__ __align__(16) u16 As[BM * LP];
  __shared__ __align__(16) u16 Bs[BM * LP];

  const int t = threadIdx.x;
  const int m0 = blockIdx.y * BM;
  const int n0 = blockIdx.x * 128;
  const int bz = blockIdx.z;
  A += (size_t)bz * Asb;
  Bt += (size_t)bz * Bsb;

  f32x4 acc[16];
#pragma unroll
  for (int i = 0; i < 16; ++i) acc[i] = (f32x4){0.f, 0.f, 0.f, 0.f};
  const int wave = t >> 6, lane = t & 63;
  const int wm = (wave >> 1) * 64, wn = (wave & 1) * 64;
  const int fr = lane & 15, fq = lane >> 4;

  for (int k0 = 0; k0 < K; k0 += BK) {
#pragma unroll
    for (int i = 0; i < 2; ++i) {
      int idx = (i * 256 + t) * 8;
      int row = idx >> 5, col = idx & 31;
      *(uint4*)&As[row * LP + col] =
          *(const uint4*)(A + (size_t)(m0 + row) * K + k0 + col);
      uint4 bv = {0u, 0u, 0u, 0u};
      if (n0 + row < N) bv = *(const uint4*)(Bt + (size_t)(n0 + row) * K + k0 + col);
      *(uint4*)&Bs[row * LP + col] = bv;
    }
    __syncthreads();
    bf16x8 af[4], bfr[4];
#pragma unroll
    for (int i = 0; i < 4; ++i)
      af[i] = *(const bf16x8*)&As[(wm + i * 16 + fr) * LP + fq * 8];
#pragma unroll
    for (int j = 0; j < 4; ++j)
      bfr[j] = *(const bf16x8*)&Bs[(wn + j * 16 + fr) * LP + fq * 8];
#pragma unroll
    for (int i = 0; i < 4; ++i)
#pragma unroll
      for (int j = 0; j < 4; ++j)
        acc[i * 4 + j] = __builtin_amdgcn_mfma_f32_16x16x32_bf16(
            af[i], bfr[j], acc[i * 4 + j], 0, 0, 0);
    __syncthreads();
  }

#pragma unroll
  for (int i = 0; i < 4; ++i) {
#pragma unroll
    for (int rr = 0; rr < 4; ++rr) {
      long gm = (long)m0 + wm + i * 16 + fq * 4 + rr;
#pragma unroll
      for (int j = 0; j < 4; ++j) {
        int gn = n0 + wn + j * 16 + fr;
        if (gn >= N) continue;
        float v = acc[i * 4 + j][rr];
        size_t oi = (size_t)bz * osb + (size_t)gm * N + gn;
        size_t ri = (size_t)gm * N + gn;
        if (MODE == 6) ((u16*)out)[oi] = f2bf(gelu_f(v + bias[(size_t)bz * bsb + gn]));
        if (MODE == 7)
          ((float*)out)[oi] = v + bias[(size_t)bz * bsb + gn] +
                              res1[(size_t)bz * r1sb + ri] +
                              res2[(size_t)bz * r2sb + ri] +
                              res3[(size_t)bz * r3sb + ri];
      }
    }
  }
}

// ---------------------------------------------------------------------------
// Barrier-free MFMA flash attention, NO-MAX softmax (scores O(+-6); masked
// lanes s=-3e38 -> exp=0). Row-sum l via ones-B MFMA. 32 Q-ROWS PER WAVE
// (R5: halved VMEM bytes/work, confirmed -74us).
// SELF-ATTN LOAD BALANCE (R10): with 512 blocks = 2/CU and tile=(flat>>3)&7,
// each CU got the SAME causal q-tile twice -> worst CU = 2x33 chunk-units
// (why self always timed == cross despite 58% work). Fix by construction:
// block j's 4 waves take complementary 32-row slices {j,15-j,16+j,31-j}
// -> per-block work = 70 units CONSTANT, balanced under any scheduler.
// Plus per-wave causal trip count nk = P + q0w + 32 (no wasted masked
// chunks). Waves are independent (own Q/Ps row; bTs read-only, one uniform
// barrier) so this is a pure index remap. Cross path unchanged.
// Block = (b,h,4 slices); 4 waves x 32 rows. Grid 512 = 2/CU.
// XCD swizzle: 64 wg/XCD -> K/V of 8 (b,h) pairs per XCD (2.2 MB < L2).
// Q [B,H,1024,64] bf16 (pre-scaled). K [B,H,1056,64]. Vt [B,H,64,1056].
// ---------------------------------------------------------------------------
template <bool IS_SELF>
__global__ __launch_bounds__(256) void fattn_k(
    const u16* __restrict__ Qg, const u16* __restrict__ Kg,
    const u16* __restrict__ Vtg, const float* __restrict__ bias_tab,
    u16* __restrict__ Out) {
  const int L = 1024, P = 30, KC = 1056;
  // XCD swizzle: 512 blocks, 8 XCDs (round-robin flat%8), 64 wg per XCD.
  const int flat = blockIdx.x;
  const int wg = (flat & 7) * 64 + (flat >> 3);
  const int h = (wg >> 3) & 15, b = wg >> 7;
  const int t = threadIdx.x, wave = t >> 6, lane = t & 63;
  const int fr = lane & 15, fq = lane >> 4;
  int q0w;
  if (IS_SELF) {
    // balanced complementary slices: {j, 15-j, 16+j, 31-j}
    const int j = wg & 7;
    const int sl = (wave == 0) ? j
                 : (wave == 1) ? (15 - j)
                 : (wave == 2) ? (16 + j)
                               : (31 - j);
    q0w = sl * 32;
  } else {
    q0w = (wg & 7) * 128 + wave * 32;
  }

  __shared__ float bTs[IS_SELF ? 1024 : 4];
  __shared__ __align__(16) u16 Ps[4][32][40];

  if (IS_SELF) {
#pragma unroll
    for (int i = 0; i < 4; ++i) bTs[t + i * 256] = bias_tab[h * 1024 + t + i * 256];
    __syncthreads();  // once per kernel
  }

  // Q fragments: two 16-row sub-tiles (A: rows q0w.., B: rows q0w+16..)
  const u16* qptr = Qg + (((size_t)(b * 16 + h)) * L + q0w + fr) * 64 + fq * 8;
  bf16x8 qa0 = *(const bf16x8*)qptr;
  bf16x8 qa1 = *(const bf16x8*)(qptr + 32);
  bf16x8 qb0 = *(const bf16x8*)(qptr + 16 * 64);
  bf16x8 qb1 = *(const bf16x8*)(qptr + 16 * 64 + 32);

  f32x4 oA[4], oB[4];
#pragma unroll
  for (int i = 0; i < 4; ++i) {
    oA[i] = (f32x4){0.f, 0.f, 0.f, 0.f};
    oB[i] = (f32x4){0.f, 0.f, 0.f, 0.f};
  }
  f32x4 olA = (f32x4){0.f, 0.f, 0.f, 0.f};
  f32x4 olB = (f32x4){0.f, 0.f, 0.f, 0.f};
  bf16x8 ones;
  {
    u16 one = 0x3F80;  // bf16 1.0
#pragma unroll
    for (int i = 0; i < 8; ++i) ((u16*)&ones)[i] = one;
  }

  // per-wave causal trip count: this wave's 32 rows see keys < P+q0w+32
  const int nk = IS_SELF ? (P + q0w + 32) : (P + L);
  const int nch = (nk + 31) >> 5;
  // per-lane fragment base pointers (identical across the block's 4 waves)
  const u16* kp = Kg + ((size_t)(b * 16 + h)) * KC * 64 + (size_t)fr * 64 + fq * 8;
  const u16* vp = Vtg + ((size_t)(b * 16 + h)) * 64 * KC + (size_t)fr * KC + fq * 8;

  bf16x8 kf0 = *(const bf16x8*)(kp + 0);
  bf16x8 kf1 = *(const bf16x8*)(kp + 32);
  bf16x8 kf2 = *(const bf16x8*)(kp + 16 * 64);
  bf16x8 kf3 = *(const bf16x8*)(kp + 16 * 64 + 32);

  // bias+mask+exp+Ps-store for one 16-row score tile; rb = row base (0/16)
  auto smax = [&](f32x4* s, int k0, int qoff, int rb) {
    const bool full = IS_SELF ? (k0 >= 32 && k0 + 31 - P <= qoff)
                              : (k0 + 31 < P + L);
    if (full) {
      if (IS_SELF) {
#pragma unroll
        for (int reg = 0; reg < 4; ++reg) {
          const int qq = qoff + fq * 4 + reg;
          s[0][reg] += bTs[qq - (k0 + fr - P)];
          s[1][reg] += bTs[qq - (k0 + 16 + fr - P)];
        }
      }
    } else {
#pragma unroll
      for (int reg = 0; reg < 4; ++reg) {
        const int qq = qoff + fq * 4 + reg;
#pragma unroll
        for (int t2 = 0; t2 < 2; ++t2) {
          const int kvi = k0 + t2 * 16 + fr;
          float sv = s[t2][reg];
          if (IS_SELF) {
            const int lk = kvi - P;
            if (lk >= 0) {
              if (lk <= qq) sv += bTs[qq - lk];
              else sv = -3.0e38f;
            }
          } else {
            if (kvi >= P + L) sv = -3.0e38f;
          }
          s[t2][reg] = sv;
        }
      }
    }
    // no-max softmax: p = exp(s); masked s=-3e38 -> p=0
#pragma unroll
    for (int reg = 0; reg < 4; ++reg) {
      Ps[wave][rb + fq * 4 + reg][fr] = f2bf_fast(__expf(s[0][reg]));
      Ps[wave][rb + fq * 4 + reg][16 + fr] = f2bf_fast(__expf(s[1][reg]));
    }
  };

  for (int ch = 0; ch < nch; ++ch) {
    const int k0 = ch * 32;
    bf16x8 vf0 = *(const bf16x8*)(vp + 0 * 16 * KC + k0);
    bf16x8 vf1 = *(const bf16x8*)(vp + 1 * 16 * KC + k0);
    bf16x8 vf2 = *(const bf16x8*)(vp + 2 * 16 * KC + k0);
    bf16x8 vf3 = *(const bf16x8*)(vp + 3 * 16 * KC + k0);
    const int k0n = (ch + 1 < nch) ? (k0 + 32) : 0;
    bf16x8 kn0 = *(const bf16x8*)(kp + (size_t)k0n * 64);
    bf16x8 kn1 = *(const bf16x8*)(kp + (size_t)k0n * 64 + 32);
    bf16x8 kn2 = *(const bf16x8*)(kp + (size_t)(k0n + 16) * 64);
    bf16x8 kn3 = *(const bf16x8*)(kp + (size_t)(k0n + 16) * 64 + 32);

    f32x4 sA[2], sB[2];
    sA[0] = (f32x4){0.f, 0.f, 0.f, 0.f};
    sA[1] = (f32x4){0.f, 0.f, 0.f, 0.f};
    sB[0] = (f32x4){0.f, 0.f, 0.f, 0.f};
    sB[1] = (f32x4){0.f, 0.f, 0.f, 0.f};
    sA[0] = __builtin_amdgcn_mfma_f32_16x16x32_bf16(qa0, kf0, sA[0], 0, 0, 0);
    sA[0] = __builtin_amdgcn_mfma_f32_16x16x32_bf16(qa1, kf1, sA[0], 0, 0, 0);
    sA[1] = __builtin_amdgcn_mfma_f32_16x16x32_bf16(qa0, kf2, sA[1], 0, 0, 0);
    sA[1] = __builtin_amdgcn_mfma_f32_16x16x32_bf16(qa1, kf3, sA[1], 0, 0, 0);
    sB[0] = __builtin_amdgcn_mfma_f32_16x16x32_bf16(qb0, kf0, sB[0], 0, 0, 0);
    sB[0] = __builtin_amdgcn_mfma_f32_16x16x32_bf16(qb1, kf1, sB[0], 0, 0, 0);
    sB[1] = __builtin_amdgcn_mfma_f32_16x16x32_bf16(qb0, kf2, sB[1], 0, 0, 0);
    sB[1] = __builtin_amdgcn_mfma_f32_16x16x32_bf16(qb1, kf3, sB[1], 0, 0, 0);

    smax(sA, k0, q0w, 0);
    smax(sB, k0, q0w + 16, 16);
    __asm__ volatile("s_waitcnt lgkmcnt(0)" ::: "memory");
    bf16x8 paA = *(const bf16x8*)&Ps[wave][fr][fq * 8];
    bf16x8 paB = *(const bf16x8*)&Ps[wave][16 + fr][fq * 8];

    // P @ V : per sub-tile 4 dim-tiles + 1 ones-tile (row-sum l)
    oA[0] = __builtin_amdgcn_mfma_f32_16x16x32_bf16(paA, vf0, oA[0], 0, 0, 0);
    oA[1] = __builtin_amdgcn_mfma_f32_16x16x32_bf16(paA, vf1, oA[1], 0, 0, 0);
    oA[2] = __builtin_amdgcn_mfma_f32_16x16x32_bf16(paA, vf2, oA[2], 0, 0, 0);
    oA[3] = __builtin_amdgcn_mfma_f32_16x16x32_bf16(paA, vf3, oA[3], 0, 0, 0);
    olA   = __builtin_amdgcn_mfma_f32_16x16x32_bf16(paA, ones, olA, 0, 0, 0);
    oB[0] = __builtin_amdgcn_mfma_f32_16x16x32_bf16(paB, vf0, oB[0], 0, 0, 0);
    oB[1] = __builtin_amdgcn_mfma_f32_16x16x32_bf16(paB, vf1, oB[1], 0, 0, 0);
    oB[2] = __builtin_amdgcn_mfma_f32_16x16x32_bf16(paB, vf2, oB[2], 0, 0, 0);
    oB[3] = __builtin_amdgcn_mfma_f32_16x16x32_bf16(paB, vf3, oB[3], 0, 0, 0);
    olB   = __builtin_amdgcn_mfma_f32_16x16x32_bf16(paB, ones, olB, 0, 0, 0);

    kf0 = kn0; kf1 = kn1; kf2 = kn2; kf3 = kn3;
  }

  float invA[4], invB[4];
#pragma unroll
  for (int reg = 0; reg < 4; ++reg) {
    invA[reg] = 1.0f / olA[reg];
    invB[reg] = 1.0f / olB[reg];
  }
#pragma unroll
  for (int dt = 0; dt < 4; ++dt) {
#pragma unroll
    for (int reg = 0; reg < 4; ++reg) {
      size_t rowA = (size_t)(b * L + q0w + fq * 4 + reg);
      Out[(rowA * 16 + h) * 64 + dt * 16 + fr] = f2bf(oA[dt][reg] * invA[reg]);
      size_t rowB = rowA + 16;
      Out[(rowB * 16 + h) * 64 + dt * 16 + fr] = f2bf(oB[dt][reg] * invB[reg]);
    }
  }
}

// ---------------------------------------------------------------------------
extern "C" void kernel_launch(void* const* d_in, const int* in_sizes, int n_in,
                              void* d_out, int out_size, void* d_ws, size_t ws_size,
                              hipStream_t stream) {
  const int B = 4, L = 1024, D = 1024, H = 16, F = 2816, AD = 64;
  const int M = B * L;  // 4096
  const int KC = 1056;

  const float* inputs  = (const float*)d_in[0];
  const float* encoded = (const float*)d_in[1];
  const float* a_wd    = (const float*)d_in[2];
  const float* a_wu    = (const float*)d_in[3];
  const float* a_bd    = (const float*)d_in[4];
  const float* a_bu    = (const float*)d_in[5];
  const float* pK      = (const float*)d_in[6];
  const float* pV      = (const float*)d_in[7];
  const float* ln1     = (const float*)d_in[8];
  const float* ln2     = (const float*)d_in[9];
  const float* ln3     = (const float*)d_in[10];
  const float* sa_wq   = (const float*)d_in[11];
  const float* sa_wk   = (const float*)d_in[12];
  const float* sa_wv   = (const float*)d_in[13];
  const float* sa_wo   = (const float*)d_in[14];
  const float* ca_wq   = (const float*)d_in[15];
  const float* ca_wk   = (const float*)d_in[16];
  const float* ca_wv   = (const float*)d_in[17];
  const float* ca_wo   = (const float*)d_in[18];
  const float* relpos  = (const float*)d_in[19];
  const float* wi0     = (const float*)d_in[20];
  const float* wi1     = (const float*)d_in[21];
  const float* wom     = (const float*)d_in[22];

  char* w = (char*)d_ws;
  size_t used = 0;
  auto alloc = [&](size_t bytes) {
    char* p = w + used;
    used += (bytes + 255) & ~(size_t)255;
    return p;
  };
  // --- weights (persistent) ---
  // The first five live CONTIGUOUSLY (8 x 1M u16) so one batched transpose
  // (z=8) fills them: [wq|wk|wv | wo | cq | ck|cv | co].
  u16* wqkvT  = (u16*)alloc((size_t)3072 * 1024 * 2);  // [wq;wk;wv]^T
  u16* woT    = (u16*)alloc((size_t)D * 1024 * 2);
  u16* cqT    = (u16*)alloc((size_t)D * 1024 * 2);     // cqkvT base (cq;ck;cv)
  u16* ckvT   = (u16*)alloc((size_t)2048 * 1024 * 2);  // [ck;cv]^T
  u16* coT    = (u16*)alloc((size_t)D * 1024 * 2);
  u16* wi01T  = (u16*)alloc((size_t)5632 * 1024 * 2);  // 16-col-block interleaved
  u16* womT   = (u16*)alloc((size_t)D * F * 2);
  u16* wdT    = (u16*)alloc((size_t)B * AD * D * 2);
  u16* wuT    = (u16*)alloc((size_t)B * D * AD * 2);
  float* bT   = (float*)alloc((size_t)H * 1024 * 4);
  // --- activations ---
  // region A (24 MiB): enc16 + xn + lz
  u16* enc16  = (u16*)alloc((size_t)M * D * 2);            // 8 MiB
  u16* xn     = (u16*)alloc((size_t)M * D * 2);            // 8 MiB
  u16* lz     = (u16*)alloc((size_t)M * D * 2);            // 8 MiB
  // region B (48.5 MiB): Kc + Vtc + qh + ao + xf
  u16* Kc     = (u16*)alloc((size_t)B * H * KC * 64 * 2);  // 8.25 MiB
  u16* Vtc    = (u16*)alloc((size_t)B * H * 64 * KC * 2);  // 8.25 MiB
  u16* qh     = (u16*)alloc((size_t)B * H * L * 64 * 2);   // 8 MiB
  u16* ao     = (u16*)alloc((size_t)M * D * 2);            // 8 MiB
  float* xf   = (float*)alloc((size_t)M * D * 4);          // 16 MiB
  float* yf   = (float*)alloc((size_t)M * D * 4);          // 16 MiB, dedicated
  u16* az1    = (u16*)alloc((size_t)B * 1024 * AD * 2);    // 0.5 MiB, dedicated
  // aliases (lifetimes disjoint; see ordering below):
  // wo-proj split-K partials: p0/q0 @ Kc (16 MiB over Kc+Vtc, dead post-fattn);
  //   p1 @ xf, q1 @ yf (combined in-place by rmsnorm_sum_k).
  float* pk0  = (float*)Kc;
  // MLP: g @ Kc (23.1 MiB over Kc+Vtc+qh, q0 dead); down-proj partials:
  //   zf0 @ enc16 (16 MiB over enc16+xn, dead), zf1 @ ao (16 MiB over ao+xf/2).
  u16* g      = Kc;
  float* zf0  = (float*)enc16;
  float* zf1  = (float*)ao;
  if (used > ws_size) return;

  dim3 tb(256);
  // Batched weight transposes.
  TSrc8 s8;
  s8.p[0] = sa_wq; s8.p[1] = sa_wk; s8.p[2] = sa_wv; s8.p[3] = sa_wo;
  s8.p[4] = ca_wq; s8.p[5] = ca_wk; s8.p[6] = ca_wv; s8.p[7] = ca_wo;
  transpose8_k<<<dim3(32, 32, 8), tb, 0, stream>>>(
      s8, wqkvT, 1024, 1024, (long)1024 * 1024, 1, 0);
  TSrc8 swi;
  swi.p[0] = wi0; swi.p[1] = wi1;
  for (int i = 2; i < 8; ++i) swi.p[i] = wi0;
  transpose8_k<<<dim3(88, 32, 2), tb, 0, stream>>>(
      swi, wi01T, 1024, 2816, 0, 2, 1);  // 16-col-block interleave, roff=z
  transpose_k<<<dim3(32, 88, 1), tb, 0, stream>>>(
      wom, womT, 2816, 1024, 0, 0, 1, 0);
  transpose_k<<<dim3(2, 32, B), tb, 0, stream>>>(
      a_wd, wdT, D, AD, (long)D * AD, (long)D * AD, 1, 0);
  transpose_k<<<dim3(32, 2, B), tb, 0, stream>>>(
      a_wu, wuT, AD, D, (long)AD * D, (long)AD * D, 1, 0);
  bias_tab_k<<<dim3(64), tb, 0, stream>>>(relpos, bT);
  cast_bf16_k<<<dim3(M * D / 4 / 256), tb, 0, stream>>>(encoded, enc16, M * D / 4);

  // ---- self attention ----
  rmsnorm_k<<<dim3(M), tb, 0, stream>>>(inputs, ln1, xn);
  gemm97<11><<<dim3(24, 32), tb, 0, stream>>>(
      xn, nullptr, wqkvT, qh, Kc, Vtc, M, 3072, 1024, 1024, 0.125f);
  prefix_fill_k<<<dim3(512), tb, 0, stream>>>(pK, pV, Kc, Vtc, 0);
  fattn_k<true><<<dim3(512), tb, 0, stream>>>(qh, Kc, Vtc, bT, ao);
  // split-K wo-proj: partials p0 @ Kc (K/V dead), p1 @ xf; combine fused
  // into rmsnorm_sum (writes xn = rmsnorm(xf_sum)*ln2 and xf = sum).
  gemm97<1><<<dim3(8, 32, 2), tb, 0, stream>>>(
      ao, nullptr, woT, pk0, xf, nullptr, M, 1024, 1024, 512, 1.f);
  rmsnorm_sum_k<<<dim3(M), tb, 0, stream>>>(pk0, xf, inputs, ln2, xn, xf);
  // ---- cross attention ----
  // merged Q+KV projection: sec0 A=xn (Q *alpha), sec1/2 A2=enc16 (K,V).
  gemm97<14><<<dim3(24, 32), tb, 0, stream>>>(
      xn, enc16, cqT, qh, Kc, Vtc, M, 3072, 1024, 1024, 0.125f);
  prefix_fill_k<<<dim3(512), tb, 0, stream>>>(pK, pV, Kc, Vtc, 1);
  fattn_k<false><<<dim3(512), tb, 0, stream>>>(qh, Kc, Vtc, nullptr, ao);
  gemm97<1><<<dim3(8, 32, 2), tb, 0, stream>>>(
      ao, nullptr, coT, pk0, yf, nullptr, M, 1024, 1024, 512, 1.f);
  rmsnorm_sum_k<<<dim3(M), tb, 0, stream>>>(pk0, yf, xf, ln3, lz, yf);
  // ---- MLP + adapter ----
  //  1) az1 = gelu(lz@wd + bd)            (dedicated az1)
  //  2) g = fused-gelu up-proj (MODE 13)  (writes Kc..qh; q0/K/V dead)
  //  3) zf0/zf1 = split-K halves of g@wom (zf0 @ enc16.., zf1 @ ao.. -- dead)
  //  4) out = az1@wu + bu + zf0 + zf1 + yf
  gemm_bt<6><<<dim3(1, 8, B), tb, 0, stream>>>(
      lz, wdT, az1, nullptr, nullptr, nullptr, a_bd, 1024, AD, D,
      (long)1024 * D, (long)AD * D, (long)AD, 0, 0, 0, (long)1024 * AD);
  gemm97<13><<<dim3(44, 32), tb, 0, stream>>>(
      lz, nullptr, wi01T, g, nullptr, nullptr, M, 5632, 1024, 1024, 1.f);
  gemm97<1><<<dim3(8, 32, 2), tb, 0, stream>>>(
      g, nullptr, womT, zf0, zf1, nullptr, M, 1024, 2816, 1408, 1.f);
  gemm_bt<7><<<dim3(8, 8, B), tb, 0, stream>>>(
      az1, wuT, d_out, zf0, zf1, yf, a_bu, 1024, 1024, AD,
      (long)1024 * AD, (long)D * AD, (long)1024, (long)1024 * 1024,
      (long)1024 * 1024, (long)1024 * 1024, (long)1024 * 1024);
  (void)in_sizes; (void)n_in; (void)out_size;
}

// Round 11
// 681.306 us; speedup vs baseline: 1.0477x; 1.0226x over previous
//
#include <hip/hip_runtime.h>

typedef unsigned short u16;
typedef __attribute__((ext_vector_type(8))) __bf16 bf16x8;
typedef __attribute__((ext_vector_type(4))) float f32x4;

__device__ __forceinline__ float bf2f(u16 u) {
  union { unsigned int i; float f; } v; v.i = ((unsigned int)u) << 16; return v.f;
}
__device__ __forceinline__ u16 f2bf(float f) {
  unsigned int x = __float_as_uint(f);
  unsigned int r = (x + 0x7fffu + ((x >> 16) & 1u)) >> 16;
  return (u16)r;
}
__device__ __forceinline__ u16 f2bf_fast(float f) {
  return (u16)((__float_as_uint(f) + 0x8000u) >> 16);
}
__device__ __forceinline__ float gelu_f(float x) {
  float u = 0.7978845608028654f * (x + 0.044715f * x * x * x);
  float t = 1.0f - 2.0f / (__expf(2.0f * u) + 1.0f);
  return 0.5f * x * (1.0f + t);
}
// async global->LDS, 16B per lane. l must be wave-uniform base.
__device__ __forceinline__ void gl_lds16(const u16* g, u16* l) {
  __builtin_amdgcn_global_load_lds(
      (const __attribute__((address_space(1))) unsigned int*)g,
      (__attribute__((address_space(3))) unsigned int*)l, 16, 0, 0);
}

// ---------------------------------------------------------------------------
__global__ __launch_bounds__(256) void cast_bf16_k(const float* __restrict__ in,
                                                   u16* __restrict__ out, int n4) {
  int i = blockIdx.x * 256 + threadIdx.x;
  if (i >= n4) return;
  float4 v = ((const float4*)in)[i];
  ushort4 o;
  o.x = f2bf(v.x); o.y = f2bf(v.y); o.z = f2bf(v.z); o.w = f2bf(v.w);
  ((ushort4*)out)[i] = o;
}

// ---------------------------------------------------------------------------
// Universal output-row mapping: row' = ((cc>>4)*rs + roff)*16 + (cc&15).
// rs=1,roff=0 -> row'=cc (plain). rs=2,roff=s -> 16-col-block interleave
// (for wi0/wi1 -> wi01T pairing consumed by gemm97 MODE 13).
// ---------------------------------------------------------------------------
__global__ __launch_bounds__(256) void transpose_k(
    const float* __restrict__ in, u16* __restrict__ out, int R, int C,
    long isb, long osb, int rs, int roff) {
  __shared__ u16 tile[32][33];
  in += (size_t)blockIdx.z * isb;
  out += (size_t)blockIdx.z * osb;
  int c0 = blockIdx.x * 32, r0 = blockIdx.y * 32;
  int tx = threadIdx.x & 31, ty = threadIdx.x >> 5;
#pragma unroll
  for (int i = 0; i < 4; ++i) {
    int rr = r0 + ty + i * 8;
    if (rr < R && c0 + tx < C) tile[ty + i * 8][tx] = f2bf(in[(size_t)rr * C + c0 + tx]);
  }
  __syncthreads();
#pragma unroll
  for (int i = 0; i < 4; ++i) {
    int cc = c0 + ty + i * 8;
    if (cc < C && r0 + tx < R) {
      int orow = (((cc >> 4) * rs + roff) << 4) + (cc & 15);
      out[(size_t)orow * R + r0 + tx] = tile[tx][ty + i * 8];
    }
  }
}

// ---------------------------------------------------------------------------
// Batched transpose: z selects source pointer from a by-value struct; dst is
// out + z*zstride. roffz: roff = z (wi0/wi1 interleave) else 0.
// ---------------------------------------------------------------------------
struct TSrc8 { const float* p[8]; };
__global__ __launch_bounds__(256) void transpose8_k(
    TSrc8 srcs, u16* __restrict__ out, int R, int C,
    long zstride, int rs, int roffz) {
  __shared__ u16 tile[32][33];
  const float* __restrict__ in = srcs.p[blockIdx.z];
  out += (size_t)blockIdx.z * zstride;
  const int roff = roffz ? blockIdx.z : 0;
  int c0 = blockIdx.x * 32, r0 = blockIdx.y * 32;
  int tx = threadIdx.x & 31, ty = threadIdx.x >> 5;
#pragma unroll
  for (int i = 0; i < 4; ++i) {
    int rr = r0 + ty + i * 8;
    if (rr < R && c0 + tx < C) tile[ty + i * 8][tx] = f2bf(in[(size_t)rr * C + c0 + tx]);
  }
  __syncthreads();
#pragma unroll
  for (int i = 0; i < 4; ++i) {
    int cc = c0 + ty + i * 8;
    if (cc < C && r0 + tx < R) {
      int orow = (((cc >> 4) * rs + roff) << 4) + (cc & 15);
      out[(size_t)orow * R + r0 + tx] = tile[tx][ty + i * 8];
    }
  }
}

// ---------------------------------------------------------------------------
__global__ __launch_bounds__(256) void bias_tab_k(const float* __restrict__ relpos,
                                                  float* __restrict__ tab) {
  int idx = blockIdx.x * 256 + threadIdx.x;  // 16*1024
  int h = idx >> 10, d = idx & 1023;
  int bucket;
  if (d < 16) bucket = d;
  else {
    int lb = 16 + (int)(logf((float)d * (1.0f / 16.0f)) * (16.0f / logf(8.0f)));
    bucket = lb < 31 ? lb : 31;
  }
  tab[idx] = relpos[h * 32 + bucket];
}

// ---------------------------------------------------------------------------
__global__ __launch_bounds__(256) void prefix_fill_k(
    const float* __restrict__ pK, const float* __restrict__ pV,
    u16* __restrict__ Kd, u16* __restrict__ Vtd, int sSel) {
  int idx = blockIdx.x * 256 + threadIdx.x;  // B*H*32*64 = 131072
  int e = idx & 63, p = (idx >> 6) & 31, h = (idx >> 11) & 15, b = idx >> 15;
  int key = (p < 30) ? p : (1024 + p);  // pads -> 1054,1055
  float kv = 0.f, vv = 0.f;
  if (p < 30) {
    size_t src = ((((size_t)(b * 2 + sSel)) * 30 + p) * 16 + h) * 64 + e;
    kv = pK[src]; vv = pV[src];
  }
  Kd[(((size_t)(b * 16 + h)) * 1056 + key) * 64 + e] = f2bf(kv);
  Vtd[(((size_t)(b * 16 + h)) * 64 + e) * 1056 + key] = f2bf(vv);
}

// ---------------------------------------------------------------------------
__global__ __launch_bounds__(256) void rmsnorm_k(const float* __restrict__ in,
                                                 const float* __restrict__ scale,
                                                 u16* __restrict__ out) {
  const int D = 1024;
  size_t base = (size_t)blockIdx.x * D;
  int t = threadIdx.x;
  float x[4];
#pragma unroll
  for (int i = 0; i < 4; ++i) x[i] = in[base + t + i * 256];
  float s = x[0] * x[0] + x[1] * x[1] + x[2] * x[2] + x[3] * x[3];
#pragma unroll
  for (int off = 1; off < 64; off <<= 1) s += __shfl_xor(s, off, 64);
  __shared__ float ws4[4];
  if ((t & 63) == 0) ws4[t >> 6] = s;
  __syncthreads();
  float tot = ws4[0] + ws4[1] + ws4[2] + ws4[3];
  float r = rsqrtf(tot * (1.0f / D) + 1e-6f);
#pragma unroll
  for (int i = 0; i < 4; ++i) {
    int c = t + i * 256;
    out[base + c] = f2bf(x[i] * r * scale[c]);
  }
}

// ---------------------------------------------------------------------------
// Split-K combine fused into rmsnorm: x = in0 + in1 + res; outs = x (f32,
// may alias in1 -- elementwise same-index read-then-write is safe);
// outn = rmsnorm(x)*scale (bf16).
// ---------------------------------------------------------------------------
__global__ __launch_bounds__(256) void rmsnorm_sum_k(
    const float* __restrict__ in0, const float* __restrict__ in1,
    const float* __restrict__ res, const float* __restrict__ scale,
    u16* __restrict__ outn, float* __restrict__ outs) {
  const int D = 1024;
  size_t base = (size_t)blockIdx.x * D;
  int t = threadIdx.x;
  float x[4];
#pragma unroll
  for (int i = 0; i < 4; ++i) {
    int c = t + i * 256;
    x[i] = in0[base + c] + in1[base + c] + res[base + c];
    outs[base + c] = x[i];
  }
  float s = x[0] * x[0] + x[1] * x[1] + x[2] * x[2] + x[3] * x[3];
#pragma unroll
  for (int off = 1; off < 64; off <<= 1) s += __shfl_xor(s, off, 64);
  __shared__ float ws4[4];
  if ((t & 63) == 0) ws4[t >> 6] = s;
  __syncthreads();
  float tot = ws4[0] + ws4[1] + ws4[2] + ws4[3];
  float r = rsqrtf(tot * (1.0f / D) + 1e-6f);
#pragma unroll
  for (int i = 0; i < 4; ++i) {
    int c = t + i * 256;
    outn[base + c] = f2bf(x[i] * r * scale[c]);
  }
}

// ---------------------------------------------------------------------------
// m97-style MFMA GEMM, BK=64 (R11): C[M][N] = A[M][K-stride] @ Bt[N][K]^T.
// 128x128 tile, 32 KiB x2 LDS, global_load_lds width-16 staging.
// BK=64 halves the vmcnt(0)+barrier drain frequency vs BK=32 (the ~20%
// structural stall of the 2-barrier m97 loop) while keeping the live
// fragment set at 8 (two kk-half passes) so VGPR/occupancy is unchanged.
// Staging: each wave fills 32 rows in 4 calls of 8 rows x 128 B
// (lane -> row=l>>3, col=(l&7)*8; LDS offset = lane*16 B, linear as
// global_load_lds requires). Requires Ks % 64 == 0 (1024/512/1408 all ok).
// K = row stride of A/Bt; Ks = K-loop length; z selects K-slice for MODE 1.
// Bijective XCD swizzle ONLY for MODE 1 (wide-N measured harmful, R7).
// Epilogue MODE:
//  1: split-K f32 partial (z=0 -> out, z=1 -> out2)
//  8: Q scatter (*alpha)
//  11: QKV scatter (sec0 Q *alpha; sec1 K +30; sec2 Vt +30)
//  13: fused gelu-gate, 16-col-block interleaved wi01T: j-tiles (2p,2p+1)
//      are (gate,lin) for the same 16 cols -> out=gelu(gate)*lin, no shfl.
//  14: like 11 but sec0 reads A (xn), sec1/2 read A2 (enc16).
// Scatter: Q [B,H,1024,64] *alpha; K [B,H,1056,64] +30; Vt [B,H,64,1056] +30
// ---------------------------------------------------------------------------
template <int MODE>
__global__ __launch_bounds__(256) void gemm97(
    const u16* __restrict__ A, const u16* __restrict__ A2,
    const u16* __restrict__ Bt, void* __restrict__ out,
    void* __restrict__ out2, void* __restrict__ out3,
    int M, int N, int K, int Ks, float alpha) {
  const int BK = 64;
  __shared__ __align__(16) u16 As[128 * 64];
  __shared__ __align__(16) u16 Bs[128 * 64];

  const int t = threadIdx.x;
  const int wave = t >> 6, lane = t & 63;
  int m0, n0;
  if (MODE == 1) {
    // XCD-aware bijective swizzle: contiguous chunk of wg per XCD.
    int wgid = blockIdx.y * gridDim.x + blockIdx.x;
    const int cpx = (gridDim.x * gridDim.y) >> 3;
    wgid = (wgid & 7) * cpx + (wgid >> 3);
    m0 = (wgid / gridDim.x) * 128;
    n0 = (wgid % gridDim.x) * 128;
  } else {
    m0 = blockIdx.y * 128;
    n0 = blockIdx.x * 128;
  }
  const int kbase = blockIdx.z * Ks;
  const int fr = lane & 15, fq = lane >> 4;
  const int wm = (wave >> 1) * 64, wn = (wave & 1) * 64;

  const u16* Ause = (MODE == 14 && n0 >= 1024) ? A2 : A;
  // staging: 4 chunks of 8 rows x 64 cols per wave, lane-linear in LDS
  const int lrow = lane >> 3;         // 0..7
  const int lcol = (lane & 7) * 8;    // 0..56 (u16 units)
  const u16* agp[4];
  const u16* bgp[4];
  u16* alp[4];
  u16* blp[4];
#pragma unroll
  for (int c = 0; c < 4; ++c) {
    int r = wave * 32 + c * 8;
    agp[c] = Ause + (size_t)(m0 + r + lrow) * K + kbase + lcol;
    bgp[c] = Bt + (size_t)(n0 + r + lrow) * K + kbase + lcol;
    alp[c] = &As[r * 64];
    blp[c] = &Bs[r * 64];
  }

  f32x4 acc[16];
#pragma unroll
  for (int i = 0; i < 16; ++i) acc[i] = (f32x4){0.f, 0.f, 0.f, 0.f};

  for (int k0 = 0; k0 < Ks; k0 += BK) {
#pragma unroll
    for (int c = 0; c < 4; ++c) gl_lds16(agp[c] + k0, alp[c]);
#pragma unroll
    for (int c = 0; c < 4; ++c) gl_lds16(bgp[c] + k0, blp[c]);
    __syncthreads();
    bf16x8 af[4], bf[4];
    // kk-half 0
#pragma unroll
    for (int i = 0; i < 4; ++i)
      af[i] = *(const bf16x8*)&As[(wm + i * 16 + fr) * 64 + fq * 8];
#pragma unroll
    for (int j = 0; j < 4; ++j)
      bf[j] = *(const bf16x8*)&Bs[(wn + j * 16 + fr) * 64 + fq * 8];
#pragma unroll
    for (int i = 0; i < 4; ++i)
#pragma unroll
      for (int j = 0; j < 4; ++j)
        acc[i * 4 + j] = __builtin_amdgcn_mfma_f32_16x16x32_bf16(
            af[i], bf[j], acc[i * 4 + j], 0, 0, 0);
    // kk-half 1
#pragma unroll
    for (int i = 0; i < 4; ++i)
      af[i] = *(const bf16x8*)&As[(wm + i * 16 + fr) * 64 + 32 + fq * 8];
#pragma unroll
    for (int j = 0; j < 4; ++j)
      bf[j] = *(const bf16x8*)&Bs[(wn + j * 16 + fr) * 64 + 32 + fq * 8];
#pragma unroll
    for (int i = 0; i < 4; ++i)
#pragma unroll
      for (int j = 0; j < 4; ++j)
        acc[i * 4 + j] = __builtin_amdgcn_mfma_f32_16x16x32_bf16(
            af[i], bf[j], acc[i * 4 + j], 0, 0, 0);
    __syncthreads();
  }

  // epilogue: D row = fq*4 + reg, col = fr
#pragma unroll
  for (int i = 0; i < 4; ++i) {
#pragma unroll
    for (int rr = 0; rr < 4; ++rr) {
      long gm = (long)m0 + wm + i * 16 + fq * 4 + rr;
      if (MODE == 13) {
#pragma unroll
        for (int p = 0; p < 2; ++p) {
          float gate = acc[i * 4 + 2 * p][rr];
          float lin = acc[i * 4 + 2 * p + 1][rr];
          int col = ((n0 + wn) >> 1) + p * 16 + fr;
          ((u16*)out)[(size_t)gm * 2816 + col] = f2bf(gelu_f(gate) * lin);
        }
        continue;
      }
#pragma unroll
      for (int j = 0; j < 4; ++j) {
        int gn = n0 + wn + j * 16 + fr;
        float v = acc[i * 4 + j][rr];
        size_t oi = (size_t)gm * N + gn;
        if (MODE == 1) {
          float* po = blockIdx.z ? (float*)out2 : (float*)out;
          po[oi] = v;
        }
        if (MODE == 8) {
          int b = (int)(gm >> 10), l = (int)(gm & 1023), h = gn >> 6, e = gn & 63;
          ((u16*)out)[(((size_t)(b * 16 + h)) * 1024 + l) * 64 + e] = f2bf(v * alpha);
        }
        if (MODE == 11 || MODE == 14) {
          int b = (int)(gm >> 10), l = (int)(gm & 1023);
          int sec = gn >> 10, nn = gn & 1023, h = nn >> 6, e = nn & 63;
          if (sec == 0)
            ((u16*)out)[(((size_t)(b * 16 + h)) * 1024 + l) * 64 + e] = f2bf(v * alpha);
          else if (sec == 1)
            ((u16*)out2)[(((size_t)(b * 16 + h)) * 1056 + 30 + l) * 64 + e] = f2bf(v);
          else
            ((u16*)out3)[(((size_t)(b * 16 + h)) * 64 + e) * 1056 + 30 + l] = f2bf(v);
        }
      }
    }
  }
}

// ---------------------------------------------------------------------------
// Small bounds-checked GEMM (VGPR staging) for adapter matmuls.
// MODE 6: bf16 out gelu(acc + biasf[n])
// MODE 7: f32 out acc + biasf + res1 + res2 + res3
// ---------------------------------------------------------------------------
template <int MODE>
__global__ __launch_bounds__(256) void gemm_bt(
    const u16* __restrict__ A, const u16* __restrict__ Bt, void* __restrict__ out,
    const float* __restrict__ res1, const float* __restrict__ res2,
    const float* __restrict__ res3, const float* __restrict__ bias,
    int M, int N, int K,
    long Asb, long Bsb, long bsb, long r1sb, long r2sb, long r3sb, long osb) {
  const int BM = 128, BK = 32, LP = 40;
  __shared__ __align__(16) u16 As[BM * LP];
  __shared__ __align__(16) u16 Bs[BM * LP];

  const int t = threadIdx.x;
  const int m0 = blockIdx.y * BM;
  const int n0 = blockIdx.x * 128;
  const int bz = blockIdx.z;
  A += (size_t)bz * Asb;
  Bt += (size_t)bz * Bsb;

  f32x4 acc[16];
#pragma unroll
  for (int i = 0; i < 16; ++i) acc[i] = (f32x4){0.f, 0.f, 0.f, 0.f};
  const int wave = t >> 6, lane = t & 63;
  const int wm = (wave >> 1) * 64, wn = (wave & 1) * 64;
  const int fr = lane & 15, fq = lane >> 4;

  for (int k0 = 0; k0 < K; k0 += BK) {
#pragma unroll
    for (int i = 0; i < 2; ++i) {
      int idx = (i * 256 + t) * 8;
      int row = idx >> 5, col = idx & 31;
      *(uint4*)&As[row * LP + col] =
          *(const uint4*)(A + (size_t)(m0 + row) * K + k0 + col);
      uint4 bv = {0u, 0u, 0u, 0u};
      if (n0 + row < N) bv = *(const uint4*)(Bt + (size_t)(n0 + row) * K + k0 + col);
      *(uint4*)&Bs[row * LP + col] = bv;
    }
    __syncthreads();
    bf16x8 af[4], bfr[4];
#pragma unroll
    for (int i = 0; i < 4; ++i)
      af[i] = *(const bf16x8*)&As[(wm + i * 16 + fr) * LP + fq * 8];
#pragma unroll
    for (int j = 0; j < 4; ++j)
      bfr[j] = *(const bf16x8*)&Bs[(wn + j * 16 + fr) * LP + fq * 8];
#pragma unroll
    for (int i = 0; i < 4; ++i)
#pragma unroll
      for (int j = 0; j < 4; ++j)
        acc[i * 4 + j] = __builtin_amdgcn_mfma_f32_16x16x32_bf16(
            af[i], bfr[j], acc[i * 4 + j], 0, 0, 0);
    __syncthreads();
  }

#pragma unroll
  for (int i = 0; i < 4; ++i) {
#pragma unroll
    for (int rr = 0; rr < 4; ++rr) {
      long gm = (long)m0 + wm + i * 16 + fq * 4 + rr;
#pragma unroll
      for (int j = 0; j < 4; ++j) {
        int gn = n0 + wn + j * 16 + fr;
        if (gn >= N) continue;
        float v = acc[i * 4 + j][rr];
        size_t oi = (size_t)bz * osb + (size_t)gm * N + gn;
        size_t ri = (size_t)gm * N + gn;
        if (MODE == 6) ((u16*)out)[oi] = f2bf(gelu_f(v + bias[(size_t)bz * bsb + gn]));
        if (MODE == 7)
          ((float*)out)[oi] = v + bias[(size_t)bz * bsb + gn] +
                              res1[(size_t)bz * r1sb + ri] +
                              res2[(size_t)bz * r2sb + ri] +
                              res3[(size_t)bz * r3sb + ri];
      }
    }
  }
}

// ---------------------------------------------------------------------------
// Barrier-free MFMA flash attention, NO-MAX softmax (scores O(+-6); masked
// lanes s=-3e38 -> exp=0). Row-sum l via ones-B MFMA. 32 Q-ROWS PER WAVE
// (R5: halved VMEM bytes/work, confirmed -74us).
// SELF-ATTN LOAD BALANCE (R10, confirmed -17us): block j's 4 waves take
// complementary 32-row slices {j,15-j,16+j,31-j} -> per-block work = 70
// units CONSTANT (balanced under any scheduler); per-wave causal trip
// count nk = P + q0w + 32. Waves independent; pure index remap.
// Block = (b,h,4 slices); 4 waves x 32 rows. Grid 512 = 2/CU.
// XCD swizzle: 64 wg/XCD -> K/V of 8 (b,h) pairs per XCD (2.2 MB < L2).
// Q [B,H,1024,64] bf16 (pre-scaled). K [B,H,1056,64]. Vt [B,H,64,1056].
// ---------------------------------------------------------------------------
template <bool IS_SELF>
__global__ __launch_bounds__(256) void fattn_k(
    const u16* __restrict__ Qg, const u16* __restrict__ Kg,
    const u16* __restrict__ Vtg, const float* __restrict__ bias_tab,
    u16* __restrict__ Out) {
  const int L = 1024, P = 30, KC = 1056;
  // XCD swizzle: 512 blocks, 8 XCDs (round-robin flat%8), 64 wg per XCD.
  const int flat = blockIdx.x;
  const int wg = (flat & 7) * 64 + (flat >> 3);
  const int h = (wg >> 3) & 15, b = wg >> 7;
  const int t = threadIdx.x, wave = t >> 6, lane = t & 63;
  const int fr = lane & 15, fq = lane >> 4;
  int q0w;
  if (IS_SELF) {
    // balanced complementary slices: {j, 15-j, 16+j, 31-j}
    const int j = wg & 7;
    const int sl = (wave == 0) ? j
                 : (wave == 1) ? (15 - j)
                 : (wave == 2) ? (16 + j)
                               : (31 - j);
    q0w = sl * 32;
  } else {
    q0w = (wg & 7) * 128 + wave * 32;
  }

  __shared__ float bTs[IS_SELF ? 1024 : 4];
  __shared__ __align__(16) u16 Ps[4][32][40];

  if (IS_SELF) {
#pragma unroll
    for (int i = 0; i < 4; ++i) bTs[t + i * 256] = bias_tab[h * 1024 + t + i * 256];
    __syncthreads();  // once per kernel
  }

  // Q fragments: two 16-row sub-tiles (A: rows q0w.., B: rows q0w+16..)
  const u16* qptr = Qg + (((size_t)(b * 16 + h)) * L + q0w + fr) * 64 + fq * 8;
  bf16x8 qa0 = *(const bf16x8*)qptr;
  bf16x8 qa1 = *(const bf16x8*)(qptr + 32);
  bf16x8 qb0 = *(const bf16x8*)(qptr + 16 * 64);
  bf16x8 qb1 = *(const bf16x8*)(qptr + 16 * 64 + 32);

  f32x4 oA[4], oB[4];
#pragma unroll
  for (int i = 0; i < 4; ++i) {
    oA[i] = (f32x4){0.f, 0.f, 0.f, 0.f};
    oB[i] = (f32x4){0.f, 0.f, 0.f, 0.f};
  }
  f32x4 olA = (f32x4){0.f, 0.f, 0.f, 0.f};
  f32x4 olB = (f32x4){0.f, 0.f, 0.f, 0.f};
  bf16x8 ones;
  {
    u16 one = 0x3F80;  // bf16 1.0
#pragma unroll
    for (int i = 0; i < 8; ++i) ((u16*)&ones)[i] = one;
  }

  // per-wave causal trip count: this wave's 32 rows see keys < P+q0w+32
  const int nk = IS_SELF ? (P + q0w + 32) : (P + L);
  const int nch = (nk + 31) >> 5;
  // per-lane fragment base pointers (identical across the block's 4 waves)
  const u16* kp = Kg + ((size_t)(b * 16 + h)) * KC * 64 + (size_t)fr * 64 + fq * 8;
  const u16* vp = Vtg + ((size_t)(b * 16 + h)) * 64 * KC + (size_t)fr * KC + fq * 8;

  bf16x8 kf0 = *(const bf16x8*)(kp + 0);
  bf16x8 kf1 = *(const bf16x8*)(kp + 32);
  bf16x8 kf2 = *(const bf16x8*)(kp + 16 * 64);
  bf16x8 kf3 = *(const bf16x8*)(kp + 16 * 64 + 32);

  // bias+mask+exp+Ps-store for one 16-row score tile; rb = row base (0/16)
  auto smax = [&](f32x4* s, int k0, int qoff, int rb) {
    const bool full = IS_SELF ? (k0 >= 32 && k0 + 31 - P <= qoff)
                              : (k0 + 31 < P + L);
    if (full) {
      if (IS_SELF) {
#pragma unroll
        for (int reg = 0; reg < 4; ++reg) {
          const int qq = qoff + fq * 4 + reg;
          s[0][reg] += bTs[qq - (k0 + fr - P)];
          s[1][reg] += bTs[qq - (k0 + 16 + fr - P)];
        }
      }
    } else {
#pragma unroll
      for (int reg = 0; reg < 4; ++reg) {
        const int qq = qoff + fq * 4 + reg;
#pragma unroll
        for (int t2 = 0; t2 < 2; ++t2) {
          const int kvi = k0 + t2 * 16 + fr;
          float sv = s[t2][reg];
          if (IS_SELF) {
            const int lk = kvi - P;
            if (lk >= 0) {
              if (lk <= qq) sv += bTs[qq - lk];
              else sv = -3.0e38f;
            }
          } else {
            if (kvi >= P + L) sv = -3.0e38f;
          }
          s[t2][reg] = sv;
        }
      }
    }
    // no-max softmax: p = exp(s); masked s=-3e38 -> p=0
#pragma unroll
    for (int reg = 0; reg < 4; ++reg) {
      Ps[wave][rb + fq * 4 + reg][fr] = f2bf_fast(__expf(s[0][reg]));
      Ps[wave][rb + fq * 4 + reg][16 + fr] = f2bf_fast(__expf(s[1][reg]));
    }
  };

  for (int ch = 0; ch < nch; ++ch) {
    const int k0 = ch * 32;
    bf16x8 vf0 = *(const bf16x8*)(vp + 0 * 16 * KC + k0);
    bf16x8 vf1 = *(const bf16x8*)(vp + 1 * 16 * KC + k0);
    bf16x8 vf2 = *(const bf16x8*)(vp + 2 * 16 * KC + k0);
    bf16x8 vf3 = *(const bf16x8*)(vp + 3 * 16 * KC + k0);
    const int k0n = (ch + 1 < nch) ? (k0 + 32) : 0;
    bf16x8 kn0 = *(const bf16x8*)(kp + (size_t)k0n * 64);
    bf16x8 kn1 = *(const bf16x8*)(kp + (size_t)k0n * 64 + 32);
    bf16x8 kn2 = *(const bf16x8*)(kp + (size_t)(k0n + 16) * 64);
    bf16x8 kn3 = *(const bf16x8*)(kp + (size_t)(k0n + 16) * 64 + 32);

    f32x4 sA[2], sB[2];
    sA[0] = (f32x4){0.f, 0.f, 0.f, 0.f};
    sA[1] = (f32x4){0.f, 0.f, 0.f, 0.f};
    sB[0] = (f32x4){0.f, 0.f, 0.f, 0.f};
    sB[1] = (f32x4){0.f, 0.f, 0.f, 0.f};
    sA[0] = __builtin_amdgcn_mfma_f32_16x16x32_bf16(qa0, kf0, sA[0], 0, 0, 0);
    sA[0] = __builtin_amdgcn_mfma_f32_16x16x32_bf16(qa1, kf1, sA[0], 0, 0, 0);
    sA[1] = __builtin_amdgcn_mfma_f32_16x16x32_bf16(qa0, kf2, sA[1], 0, 0, 0);
    sA[1] = __builtin_amdgcn_mfma_f32_16x16x32_bf16(qa1, kf3, sA[1], 0, 0, 0);
    sB[0] = __builtin_amdgcn_mfma_f32_16x16x32_bf16(qb0, kf0, sB[0], 0, 0, 0);
    sB[0] = __builtin_amdgcn_mfma_f32_16x16x32_bf16(qb1, kf1, sB[0], 0, 0, 0);
    sB[1] = __builtin_amdgcn_mfma_f32_16x16x32_bf16(qb0, kf2, sB[1], 0, 0, 0);
    sB[1] = __builtin_amdgcn_mfma_f32_16x16x32_bf16(qb1, kf3, sB[1], 0, 0, 0);

    smax(sA, k0, q0w, 0);
    smax(sB, k0, q0w + 16, 16);
    __asm__ volatile("s_waitcnt lgkmcnt(0)" ::: "memory");
    bf16x8 paA = *(const bf16x8*)&Ps[wave][fr][fq * 8];
    bf16x8 paB = *(const bf16x8*)&Ps[wave][16 + fr][fq * 8];

    // P @ V : per sub-tile 4 dim-tiles + 1 ones-tile (row-sum l)
    oA[0] = __builtin_amdgcn_mfma_f32_16x16x32_bf16(paA, vf0, oA[0], 0, 0, 0);
    oA[1] = __builtin_amdgcn_mfma_f32_16x16x32_bf16(paA, vf1, oA[1], 0, 0, 0);
    oA[2] = __builtin_amdgcn_mfma_f32_16x16x32_bf16(paA, vf2, oA[2], 0, 0, 0);
    oA[3] = __builtin_amdgcn_mfma_f32_16x16x32_bf16(paA, vf3, oA[3], 0, 0, 0);
    olA   = __builtin_amdgcn_mfma_f32_16x16x32_bf16(paA, ones, olA, 0, 0, 0);
    oB[0] = __builtin_amdgcn_mfma_f32_16x16x32_bf16(paB, vf0, oB[0], 0, 0, 0);
    oB[1] = __builtin_amdgcn_mfma_f32_16x16x32_bf16(paB, vf1, oB[1], 0, 0, 0);
    oB[2] = __builtin_amdgcn_mfma_f32_16x16x32_bf16(paB, vf2, oB[2], 0, 0, 0);
    oB[3] = __builtin_amdgcn_mfma_f32_16x16x32_bf16(paB, vf3, oB[3], 0, 0, 0);
    olB   = __builtin_amdgcn_mfma_f32_16x16x32_bf16(paB, ones, olB, 0, 0, 0);

    kf0 = kn0; kf1 = kn1; kf2 = kn2; kf3 = kn3;
  }

  float invA[4], invB[4];
#pragma unroll
  for (int reg = 0; reg < 4; ++reg) {
    invA[reg] = 1.0f / olA[reg];
    invB[reg] = 1.0f / olB[reg];
  }
#pragma unroll
  for (int dt = 0; dt < 4; ++dt) {
#pragma unroll
    for (int reg = 0; reg < 4; ++reg) {
      size_t rowA = (size_t)(b * L + q0w + fq * 4 + reg);
      Out[(rowA * 16 + h) * 64 + dt * 16 + fr] = f2bf(oA[dt][reg] * invA[reg]);
      size_t rowB = rowA + 16;
      Out[(rowB * 16 + h) * 64 + dt * 16 + fr] = f2bf(oB[dt][reg] * invB[reg]);
    }
  }
}

// ---------------------------------------------------------------------------
extern "C" void kernel_launch(void* const* d_in, const int* in_sizes, int n_in,
                              void* d_out, int out_size, void* d_ws, size_t ws_size,
                              hipStream_t stream) {
  const int B = 4, L = 1024, D = 1024, H = 16, F = 2816, AD = 64;
  const int M = B * L;  // 4096
  const int KC = 1056;

  const float* inputs  = (const float*)d_in[0];
  const float* encoded = (const float*)d_in[1];
  const float* a_wd    = (const float*)d_in[2];
  const float* a_wu    = (const float*)d_in[3];
  const float* a_bd    = (const float*)d_in[4];
  const float* a_bu    = (const float*)d_in[5];
  const float* pK      = (const float*)d_in[6];
  const float* pV      = (const float*)d_in[7];
  const float* ln1     = (const float*)d_in[8];
  const float* ln2     = (const float*)d_in[9];
  const float* ln3     = (const float*)d_in[10];
  const float* sa_wq   = (const float*)d_in[11];
  const float* sa_wk   = (const float*)d_in[12];
  const float* sa_wv   = (const float*)d_in[13];
  const float* sa_wo   = (const float*)d_in[14];
  const float* ca_wq   = (const float*)d_in[15];
  const float* ca_wk   = (const float*)d_in[16];
  const float* ca_wv   = (const float*)d_in[17];
  const float* ca_wo   = (const float*)d_in[18];
  const float* relpos  = (const float*)d_in[19];
  const float* wi0     = (const float*)d_in[20];
  const float* wi1     = (const float*)d_in[21];
  const float* wom     = (const float*)d_in[22];

  char* w = (char*)d_ws;
  size_t used = 0;
  auto alloc = [&](size_t bytes) {
    char* p = w + used;
    used += (bytes + 255) & ~(size_t)255;
    return p;
  };
  // --- weights (persistent) ---
  // The first five live CONTIGUOUSLY (8 x 1M u16) so one batched transpose
  // (z=8) fills them: [wq|wk|wv | wo | cq | ck|cv | co].
  u16* wqkvT  = (u16*)alloc((size_t)3072 * 1024 * 2);  // [wq;wk;wv]^T
  u16* woT    = (u16*)alloc((size_t)D * 1024 * 2);
  u16* cqT    = (u16*)alloc((size_t)D * 1024 * 2);     // cqkvT base (cq;ck;cv)
  u16* ckvT   = (u16*)alloc((size_t)2048 * 1024 * 2);  // [ck;cv]^T
  u16* coT    = (u16*)alloc((size_t)D * 1024 * 2);
  u16* wi01T  = (u16*)alloc((size_t)5632 * 1024 * 2);  // 16-col-block interleaved
  u16* womT   = (u16*)alloc((size_t)D * F * 2);
  u16* wdT    = (u16*)alloc((size_t)B * AD * D * 2);
  u16* wuT    = (u16*)alloc((size_t)B * D * AD * 2);
  float* bT   = (float*)alloc((size_t)H * 1024 * 4);
  // --- activations ---
  // region A (24 MiB): enc16 + xn + lz
  u16* enc16  = (u16*)alloc((size_t)M * D * 2);            // 8 MiB
  u16* xn     = (u16*)alloc((size_t)M * D * 2);            // 8 MiB
  u16* lz     = (u16*)alloc((size_t)M * D * 2);            // 8 MiB
  // region B (48.5 MiB): Kc + Vtc + qh + ao + xf
  u16* Kc     = (u16*)alloc((size_t)B * H * KC * 64 * 2);  // 8.25 MiB
  u16* Vtc    = (u16*)alloc((size_t)B * H * 64 * KC * 2);  // 8.25 MiB
  u16* qh     = (u16*)alloc((size_t)B * H * L * 64 * 2);   // 8 MiB
  u16* ao     = (u16*)alloc((size_t)M * D * 2);            // 8 MiB
  float* xf   = (float*)alloc((size_t)M * D * 4);          // 16 MiB
  float* yf   = (float*)alloc((size_t)M * D * 4);          // 16 MiB, dedicated
  u16* az1    = (u16*)alloc((size_t)B * 1024 * AD * 2);    // 0.5 MiB, dedicated
  // aliases (lifetimes disjoint; see ordering below):
  // wo-proj split-K partials: p0/q0 @ Kc (16 MiB over Kc+Vtc, dead post-fattn);
  //   p1 @ xf, q1 @ yf (combined in-place by rmsnorm_sum_k).
  float* pk0  = (float*)Kc;
  // MLP: g @ Kc (23.1 MiB over Kc+Vtc+qh, q0 dead); down-proj partials:
  //   zf0 @ enc16 (16 MiB over enc16+xn, dead), zf1 @ ao (16 MiB over ao+xf/2).
  u16* g      = Kc;
  float* zf0  = (float*)enc16;
  float* zf1  = (float*)ao;
  if (used > ws_size) return;

  dim3 tb(256);
  // Batched weight transposes.
  TSrc8 s8;
  s8.p[0] = sa_wq; s8.p[1] = sa_wk; s8.p[2] = sa_wv; s8.p[3] = sa_wo;
  s8.p[4] = ca_wq; s8.p[5] = ca_wk; s8.p[6] = ca_wv; s8.p[7] = ca_wo;
  transpose8_k<<<dim3(32, 32, 8), tb, 0, stream>>>(
      s8, wqkvT, 1024, 1024, (long)1024 * 1024, 1, 0);
  TSrc8 swi;
  swi.p[0] = wi0; swi.p[1] = wi1;
  for (int i = 2; i < 8; ++i) swi.p[i] = wi0;
  transpose8_k<<<dim3(88, 32, 2), tb, 0, stream>>>(
      swi, wi01T, 1024, 2816, 0, 2, 1);  // 16-col-block interleave, roff=z
  transpose_k<<<dim3(32, 88, 1), tb, 0, stream>>>(
      wom, womT, 2816, 1024, 0, 0, 1, 0);
  transpose_k<<<dim3(2, 32, B), tb, 0, stream>>>(
      a_wd, wdT, D, AD, (long)D * AD, (long)D * AD, 1, 0);
  transpose_k<<<dim3(32, 2, B), tb, 0, stream>>>(
      a_wu, wuT, AD, D, (long)AD * D, (long)AD * D, 1, 0);
  bias_tab_k<<<dim3(64), tb, 0, stream>>>(relpos, bT);
  cast_bf16_k<<<dim3(M * D / 4 / 256), tb, 0, stream>>>(encoded, enc16, M * D / 4);

  // ---- self attention ----
  rmsnorm_k<<<dim3(M), tb, 0, stream>>>(inputs, ln1, xn);
  gemm97<11><<<dim3(24, 32), tb, 0, stream>>>(
      xn, nullptr, wqkvT, qh, Kc, Vtc, M, 3072, 1024, 1024, 0.125f);
  prefix_fill_k<<<dim3(512), tb, 0, stream>>>(pK, pV, Kc, Vtc, 0);
  fattn_k<true><<<dim3(512), tb, 0, stream>>>(qh, Kc, Vtc, bT, ao);
  // split-K wo-proj: partials p0 @ Kc (K/V dead), p1 @ xf; combine fused
  // into rmsnorm_sum (writes xn = rmsnorm(xf_sum)*ln2 and xf = sum).
  gemm97<1><<<dim3(8, 32, 2), tb, 0, stream>>>(
      ao, nullptr, woT, pk0, xf, nullptr, M, 1024, 1024, 512, 1.f);
  rmsnorm_sum_k<<<dim3(M), tb, 0, stream>>>(pk0, xf, inputs, ln2, xn, xf);
  // ---- cross attention ----
  // merged Q+KV projection: sec0 A=xn (Q *alpha), sec1/2 A2=enc16 (K,V).
  gemm97<14><<<dim3(24, 32), tb, 0, stream>>>(
      xn, enc16, cqT, qh, Kc, Vtc, M, 3072, 1024, 1024, 0.125f);
  prefix_fill_k<<<dim3(512), tb, 0, stream>>>(pK, pV, Kc, Vtc, 1);
  fattn_k<false><<<dim3(512), tb, 0, stream>>>(qh, Kc, Vtc, nullptr, ao);
  gemm97<1><<<dim3(8, 32, 2), tb, 0, stream>>>(
      ao, nullptr, coT, pk0, yf, nullptr, M, 1024, 1024, 512, 1.f);
  rmsnorm_sum_k<<<dim3(M), tb, 0, stream>>>(pk0, yf, xf, ln3, lz, yf);
  // ---- MLP + adapter ----
  //  1) az1 = gelu(lz@wd + bd)            (dedicated az1)
  //  2) g = fused-gelu up-proj (MODE 13)  (writes Kc..qh; q0/K/V dead)
  //  3) zf0/zf1 = split-K halves of g@wom (zf0 @ enc16.., zf1 @ ao.. -- dead)
  //  4) out = az1@wu + bu + zf0 + zf1 + yf
  gemm_bt<6><<<dim3(1, 8, B), tb, 0, stream>>>(
      lz, wdT, az1, nullptr, nullptr, nullptr, a_bd, 1024, AD, D,
      (long)1024 * D, (long)AD * D, (long)AD, 0, 0, 0, (long)1024 * AD);
  gemm97<13><<<dim3(44, 32), tb, 0, stream>>>(
      lz, nullptr, wi01T, g, nullptr, nullptr, M, 5632, 1024, 1024, 1.f);
  gemm97<1><<<dim3(8, 32, 2), tb, 0, stream>>>(
      g, nullptr, womT, zf0, zf1, nullptr, M, 1024, 2816, 1408, 1.f);
  gemm_bt<7><<<dim3(8, 8, B), tb, 0, stream>>>(
      az1, wuT, d_out, zf0, zf1, yf, a_bu, 1024, 1024, AD,
      (long)1024 * AD, (long)D * AD, (long)1024, (long)1024 * 1024,
      (long)1024 * 1024, (long)1024 * 1024, (long)1024 * 1024);
  (void)in_sizes; (void)n_in; (void)out_size;
}